// Round 1
// baseline (7620.036 us; speedup 1.0000x reference)
//
#include <hip/hip_runtime.h>
#include <math.h>

// ---------------- constants (match reference) ----------------
constexpr int Bsz   = 2;
constexpr int Tseq  = 512;
constexpr int Mtok  = Bsz * Tseq;      // 1024 tokens
constexpr int Dm    = 768;
constexpr int DINc  = 1536;
constexpr int Hn    = 24;
constexpr int HD    = 64;
constexpr int NS    = 64;
constexpr int KC    = 4;
constexpr int DPROJc = 2*DINc + 2*NS + Hn;  // 3224
constexpr int CONVDc = DINc + 2*NS;         // 1664
constexpr int NL    = 12;
constexpr int SPL   = 6;
constexpr int LLO   = 6;
constexpr int NCH   = 8;                   // chunks of 64 along T
constexpr int Vv    = 50288;
constexpr float EPSc = 1e-5f;
constexpr int NLOOPS = 3;                  // n_loops (static in setup_inputs)

#define DEVI __device__ __forceinline__

DEVI float siluf(float x){ return x / (1.0f + expf(-x)); }
DEVI float softplusf(float x){ return (x > 20.0f) ? x : log1pf(expf(x)); }

DEVI float blk_reduce256(float v, float* sh){
  #pragma unroll
  for (int o = 32; o; o >>= 1) v += __shfl_down(v, o);
  int lane = threadIdx.x & 63, w = threadIdx.x >> 6;
  if (lane == 0) sh[w] = v;
  __syncthreads();
  return sh[0] + sh[1] + sh[2] + sh[3];
}

// ---------------- small kernels ----------------
__global__ void k_embed(const int* __restrict__ ids, const float* __restrict__ emb,
                        float* __restrict__ x){
  int m = blockIdx.x;
  int id = ids[m];
  const float4* src = (const float4*)(emb + (size_t)id * Dm);
  float4* dst = (float4*)(x + (size_t)m * Dm);
  int i = threadIdx.x;            // blockDim = 192 = 768/4
  dst[i] = src[i];
}

// res = x + res ; u = rms(res) * w
__global__ __launch_bounds__(256) void k_addrms(const float* __restrict__ xin,
    float* __restrict__ res, float* __restrict__ u, const float* __restrict__ w){
  int m = blockIdx.x, tid = threadIdx.x;
  __shared__ float sh[4];
  const float* xr = xin + (size_t)m*Dm;
  float* rr = res + (size_t)m*Dm;
  float r[3]; float ss = 0.f;
  #pragma unroll
  for (int k=0;k<3;k++){ int e = tid + k*256; float v = xr[e] + rr[e]; r[k]=v; ss += v*v; }
  ss = blk_reduce256(ss, sh);
  float rs = 1.0f / sqrtf(ss/(float)Dm + EPSc);
  #pragma unroll
  for (int k=0;k<3;k++){ int e = tid + k*256; rr[e] = r[k]; u[(size_t)m*Dm+e] = r[k]*rs*w[e]; }
}

// out = rms(in) * w   (in == out allowed: whole row handled by one block)
__global__ __launch_bounds__(256) void k_rms(const float* __restrict__ xin,
    float* __restrict__ out, const float* __restrict__ w){
  int m = blockIdx.x, tid = threadIdx.x;
  __shared__ float sh[4];
  const float* xr = xin + (size_t)m*Dm;
  float r[3]; float ss = 0.f;
  #pragma unroll
  for (int k=0;k<3;k++){ int e = tid + k*256; float v = xr[e]; r[k]=v; ss += v*v; }
  ss = blk_reduce256(ss, sh);
  float rs = 1.0f / sqrtf(ss/(float)Dm + EPSc);
  #pragma unroll
  for (int k=0;k<3;k++){ int e = tid + k*256; out[(size_t)m*Dm+e] = r[k]*rs*w[e]; }
}

// x = rope(x + gate*xp, loop_i)
__global__ __launch_bounds__(128) void k_liferope(float* __restrict__ x,
    const float* __restrict__ xp, const float* __restrict__ gate, float iF){
  int m = blockIdx.x, tid = threadIdx.x;
  float* xr = x + (size_t)m*Dm;
  const float* pr = xp + (size_t)m*Dm;
  #pragma unroll
  for (int k=0;k<3;k++){
    int j = tid + k*128;               // pair index < 384
    int d0 = 2*j, d1 = d0+1;
    float v0 = xr[d0] + gate[d0]*pr[d0];
    float v1 = xr[d1] + gate[d1]*pr[d1];
    float invf = expf(-9.210340371976184f * ((float)(2*j) * (1.0f/768.0f)));
    float f = iF * invf;
    float cv = cosf(f), sv = sinf(f);
    xr[d0] = v0*cv - v1*sv;
    xr[d1] = v1*cv + v0*sv;
  }
}

// ---------------- GEMM: C[M x N] = A[M x K] * Bw[N x K]^T ----------------
// BM=128, BN=64, BK=16, 256 threads, 8x4 micro-tile. M fixed = 1024 (grid.y = 8).
// If gridDim.z > 1: split-K, writes raw partial to C + z*M*N (alpha/accum ignored).
__global__ __launch_bounds__(256) void k_gemm(const float* __restrict__ A,
    const float* __restrict__ Bw, float* __restrict__ C,
    int Nd, int Kd, float alpha, int accum){
  __shared__ float As[16][132];
  __shared__ float Bs[16][68];
  int n0 = blockIdx.x * 64;
  int m0 = blockIdx.y * 128;
  int KS = gridDim.z;
  int kbeg = blockIdx.z * (Kd / KS);
  int kend = kbeg + Kd / KS;
  int tid = threadIdx.x;
  int tx = tid & 15, ty = tid >> 4;
  int kg = tid & 3;        // k-group of 4 floats
  int rA = tid >> 2;       // 0..63
  float acc[8][4] = {};
  for (int k0 = kbeg; k0 < kend; k0 += 16){
    #pragma unroll
    for (int p=0;p<2;p++){
      int r = rA + p*64;
      float4 v = *(const float4*)(A + (size_t)(m0 + r)*Kd + k0 + 4*kg);
      As[4*kg+0][r]=v.x; As[4*kg+1][r]=v.y; As[4*kg+2][r]=v.z; As[4*kg+3][r]=v.w;
    }
    {
      int r = rA; int n = n0 + r;
      float4 v = make_float4(0.f,0.f,0.f,0.f);
      if (n < Nd) v = *(const float4*)(Bw + (size_t)n*Kd + k0 + 4*kg);
      Bs[4*kg+0][r]=v.x; Bs[4*kg+1][r]=v.y; Bs[4*kg+2][r]=v.z; Bs[4*kg+3][r]=v.w;
    }
    __syncthreads();
    #pragma unroll
    for (int kk=0; kk<16; kk++){
      float4 a0 = *(const float4*)&As[kk][8*ty];
      float4 a1 = *(const float4*)&As[kk][8*ty+4];
      float4 b  = *(const float4*)&Bs[kk][4*tx];
      float av[8] = {a0.x,a0.y,a0.z,a0.w,a1.x,a1.y,a1.z,a1.w};
      float bv[4] = {b.x,b.y,b.z,b.w};
      #pragma unroll
      for (int i=0;i<8;i++)
        #pragma unroll
        for (int j=0;j<4;j++) acc[i][j] += av[i]*bv[j];
    }
    __syncthreads();
  }
  float* Cb = C;
  if (KS > 1) Cb = C + (size_t)blockIdx.z * (size_t)Mtok * Nd;
  #pragma unroll
  for (int i=0;i<8;i++){
    int m = m0 + 8*ty + i;
    #pragma unroll
    for (int j=0;j<4;j++){
      int n = n0 + 4*tx + j;
      if (n < Nd){
        size_t idx = (size_t)m*Nd + n;
        if (KS > 1) Cb[idx] = acc[i][j];
        else { float v = alpha*acc[i][j]; Cb[idx] = accum ? Cb[idx]+v : v; }
      }
    }
  }
}

// C = (accum ? C : 0) + sum_s part[s]
__global__ void k_ksum(const float* __restrict__ part, float* __restrict__ C,
                       int Nd, int KS, int accum){
  size_t e = (size_t)blockIdx.x*256 + threadIdx.x;
  size_t tot = (size_t)Mtok*Nd;
  if (e >= tot) return;
  float v = 0.f;
  for (int s=0;s<KS;s++) v += part[(size_t)s*tot + e];
  C[e] = accum ? C[e] + v : v;
}

// Weff = W + 2 * Bl @ Al   (Bl: N x 8, Al: 8 x K)
__global__ void k_lora_merge(const float* __restrict__ W, const float* __restrict__ Bl,
    const float* __restrict__ Al, float* __restrict__ out, int Nd, int Kd){
  size_t e = (size_t)blockIdx.x*256 + threadIdx.x;
  if (e >= (size_t)Nd*Kd) return;
  int n = (int)(e / Kd), k = (int)(e % Kd);
  float s = W[e];
  #pragma unroll
  for (int r=0;r<8;r++) s += 2.0f * Bl[n*8+r] * Al[(size_t)r*Kd + k];
  out[e] = s;
}

// fallback rank-8 kernels (used only if ws too small to merge weights)
__global__ __launch_bounds__(256) void k_rank8a(const float* __restrict__ A,
    const float* __restrict__ W8, float* __restrict__ outp, int Kd){
  extern __shared__ float Ws[];  // 8*Kd floats
  int tid = threadIdx.x;
  for (int e = tid; e < 8*Kd; e += 256) Ws[e] = W8[e];
  __syncthreads();
  int r = blockIdx.x*64 + (tid >> 2);
  int q = tid & 3;
  const float* Ar = A + (size_t)r*Kd;
  float a0=0.f, a1=0.f;
  for (int k=0;k<Kd;k+=4){
    float4 av = *(const float4*)(Ar + k);
    float4 w0 = *(const float4*)&Ws[q*Kd + k];
    float4 w1 = *(const float4*)&Ws[(q+4)*Kd + k];
    a0 += av.x*w0.x + av.y*w0.y + av.z*w0.z + av.w*w0.w;
    a1 += av.x*w1.x + av.y*w1.y + av.z*w1.z + av.w*w1.w;
  }
  outp[r*8+q] = a0; outp[r*8+q+4] = a1;
}
__global__ void k_rank8b(const float* __restrict__ Tm, const float* __restrict__ W,
    float* __restrict__ C, int Nd){
  size_t gid = (size_t)blockIdx.x*256 + threadIdx.x;
  if (gid >= (size_t)Mtok*Nd) return;
  int m = (int)(gid / Nd), n = (int)(gid % Nd);
  const float* tr = Tm + m*8;
  const float* wr = W + (size_t)n*8;
  float s = 0.f;
  #pragma unroll
  for (int r=0;r<8;r++) s += tr[r]*wr[r];
  C[gid] += 2.0f*s;
}

// ---------------- conv + dt ----------------
__global__ __launch_bounds__(256) void k_conv(const float* __restrict__ zx,
    const float* __restrict__ cw, const float* __restrict__ cb,
    const float* __restrict__ dtb, float* __restrict__ xh, float* __restrict__ Bm,
    float* __restrict__ Cm, float* __restrict__ dtsp){
  int m = blockIdx.x; int b = m >> 9; int t = m & 511;
  int c = blockIdx.y*256 + threadIdx.x;
  if (c < CONVDc){
    float accv = cb[c];
    #pragma unroll
    for (int k=0;k<KC;k++){
      int tt = t + k - (KC-1);
      if (tt >= 0) accv += cw[c*KC + k] * zx[(size_t)(b*Tseq + tt)*DPROJc + DINc + c];
    }
    float v = siluf(accv);
    if (c < DINc)            xh[(size_t)m*DINc + c] = v;
    else if (c < DINc + NS)  Bm[m*NS + (c - DINc)] = v;
    else                     Cm[m*NS + (c - DINc - NS)] = v;
  } else if (c < CONVDc + Hn){
    int h = c - CONVDc;
    float xv = zx[(size_t)m*DPROJc + DINc + CONVDc + h] + dtb[h];
    dtsp[m*Hn + h] = softplusf(xv);
  }
}

// ---------------- SSM scan (SSD chunked, Q=64, NCH=8) ----------------
// cum[bh][t]: inclusive within-chunk prefix of s_t = dt_t * A_h
__global__ __launch_bounds__(512) void k_cumlog(const float* __restrict__ dtsp,
    const float* __restrict__ alog, float* __restrict__ cum){
  int bh = blockIdx.x; int b = bh / Hn, h = bh % Hn;
  int lane = threadIdx.x & 63, w = threadIdx.x >> 6;
  int t = w*64 + lane;
  float Av = -expf(alog[h]);
  float s = dtsp[(b*Tseq + t)*Hn + h] * Av;
  #pragma unroll
  for (int o=1;o<64;o<<=1){ float v = __shfl_up(s, o); if (lane >= o) s += v; }
  cum[bh*Tseq + t] = s;
}

// S[bh][c][n][p] = sum_t exp(cum_end - cum_t)*dt_t * x_t[p] * B_t[n]
__global__ __launch_bounds__(256) void k_s1(const float* __restrict__ xh,
    const float* __restrict__ Bm, const float* __restrict__ cum,
    const float* __restrict__ dtsp, float* __restrict__ S){
  int bh = blockIdx.x; int b = bh / Hn, h = bh % Hn; int c = blockIdx.y;
  __shared__ float Xc[64][64];
  __shared__ float Bc[64][64];
  __shared__ float wv[64];
  int tid = threadIdx.x;
  int base_m = b*Tseq + c*64;
  for (int e = tid; e < 4096; e += 256){
    int t = e >> 6, p = e & 63;
    Xc[t][p] = xh[(size_t)(base_m + t)*DINc + h*64 + p];
    Bc[t][p] = Bm[(base_m + t)*NS + p];
  }
  if (tid < 64){
    float ce = cum[bh*Tseq + c*64 + 63];
    wv[tid] = expf(ce - cum[bh*Tseq + c*64 + tid]) * dtsp[(base_m + tid)*Hn + h];
  }
  __syncthreads();
  int tx = tid & 15, ty = tid >> 4;
  int nn0 = 4*tx, p0 = 4*ty;
  float acc[4][4] = {};
  #pragma unroll 4
  for (int t=0;t<64;t++){
    float4 xv = *(const float4*)&Xc[t][p0];
    float4 bv = *(const float4*)&Bc[t][nn0];
    float wt = wv[t];
    float wx[4] = {wt*xv.x, wt*xv.y, wt*xv.z, wt*xv.w};
    float bb[4] = {bv.x, bv.y, bv.z, bv.w};
    #pragma unroll
    for (int i=0;i<4;i++)
      #pragma unroll
      for (int j=0;j<4;j++) acc[i][j] += wx[i]*bb[j];
  }
  float* Sb = S + ((size_t)(bh*NCH + c))*4096;
  #pragma unroll
  for (int j=0;j<4;j++){
    float4 o = make_float4(acc[0][j], acc[1][j], acc[2][j], acc[3][j]);
    *(float4*)&Sb[(nn0+j)*64 + p0] = o;
  }
}

// sequential over chunks: hst[bh][c] = state at chunk start
__global__ void k_s2(const float* __restrict__ S, const float* __restrict__ cum,
                     float* __restrict__ hst){
  int gid = blockIdx.x*256 + threadIdx.x;   // 48*4096 threads
  int bh = gid >> 12; int e = gid & 4095;
  float hv = 0.f;
  #pragma unroll
  for (int c=0;c<NCH;c++){
    size_t idx = ((size_t)(bh*NCH + c))*4096 + e;
    hst[idx] = hv;
    float Ac = expf(cum[bh*Tseq + c*64 + 63]);
    hv = Ac*hv + S[idx];
  }
}

// within-chunk outputs + state term + D skip
__global__ __launch_bounds__(256) void k_s3(const float* __restrict__ xh,
    const float* __restrict__ Bm, const float* __restrict__ Cm,
    const float* __restrict__ cum, const float* __restrict__ dtsp,
    const float* __restrict__ hst, const float* __restrict__ Dsk,
    float* __restrict__ y){
  int bh = blockIdx.x; int b = bh / Hn, h = bh % Hn; int c = blockIdx.y;
  __shared__ float CcT[64][68];
  __shared__ float BcT[64][68];   // reused for M_T
  __shared__ float Xc[64][64];    // reused for h_start^T
  __shared__ float cumS[64];
  __shared__ float dtS[64];
  int tid = threadIdx.x;
  int base_m = b*Tseq + c*64;
  for (int e = tid; e < 4096; e += 256){
    int t = e >> 6, n = e & 63;
    CcT[n][t] = Cm[(base_m + t)*NS + n];
    BcT[n][t] = Bm[(base_m + t)*NS + n];
    Xc[t][n]  = xh[(size_t)(base_m + t)*DINc + h*64 + n];
  }
  if (tid < 64){
    cumS[tid] = cum[bh*Tseq + c*64 + tid];
    dtS[tid]  = dtsp[(base_m + tid)*Hn + h];
  }
  __syncthreads();
  int tx = tid & 15, ty = tid >> 4;
  int t0 = 4*tx, s0 = 4*ty;
  // G[t][s] = C_t . B_s
  float G[4][4] = {};
  #pragma unroll 4
  for (int n=0;n<64;n++){
    float4 cv = *(const float4*)&CcT[n][t0];
    float4 bv = *(const float4*)&BcT[n][s0];
    float ca[4]={cv.x,cv.y,cv.z,cv.w}, ba[4]={bv.x,bv.y,bv.z,bv.w};
    #pragma unroll
    for (int i=0;i<4;i++)
      #pragma unroll
      for (int j=0;j<4;j++) G[i][j] += ca[i]*ba[j];
  }
  __syncthreads();
  // M_T[s][t] = (s<=t) ? exp(cum_t - cum_s)*dt_s*G : 0   (overwrite BcT)
  #pragma unroll
  for (int j=0;j<4;j++){
    int s = s0 + j;
    float4 o;
    float* op = (float*)&o;
    #pragma unroll
    for (int i=0;i<4;i++){
      int t = t0 + i;
      op[i] = (s <= t) ? expf(cumS[t] - cumS[s]) * dtS[s] * G[i][j] : 0.f;
    }
    *(float4*)&BcT[s][t0] = o;
  }
  __syncthreads();
  int p0 = s0;
  float accL[4][4] = {};
  #pragma unroll 4
  for (int s=0;s<64;s++){
    float4 mv = *(const float4*)&BcT[s][t0];
    float4 xv = *(const float4*)&Xc[s][p0];
    float ma[4]={mv.x,mv.y,mv.z,mv.w}, xa[4]={xv.x,xv.y,xv.z,xv.w};
    #pragma unroll
    for (int i=0;i<4;i++)
      #pragma unroll
      for (int j=0;j<4;j++) accL[i][j] += ma[i]*xa[j];
  }
  __syncthreads();
  {
    const float* hb = hst + ((size_t)(bh*NCH + c))*4096;   // [n][p]
    for (int e = tid; e < 4096; e += 256) ((float*)Xc)[e] = hb[e];
  }
  __syncthreads();
  float accS[4][4] = {};
  #pragma unroll 4
  for (int n=0;n<64;n++){
    float4 cv = *(const float4*)&CcT[n][t0];
    float4 hv = *(const float4*)&((float*)Xc)[n*64 + p0];
    float ca[4]={cv.x,cv.y,cv.z,cv.w}, ha[4]={hv.x,hv.y,hv.z,hv.w};
    #pragma unroll
    for (int i=0;i<4;i++)
      #pragma unroll
      for (int j=0;j<4;j++) accS[i][j] += ca[i]*ha[j];
  }
  float Dh = Dsk[h];
  #pragma unroll
  for (int i=0;i<4;i++){
    int t = t0 + i;
    int m = base_m + t;
    float Pt = expf(cumS[t]);
    float4 xg = *(const float4*)&xh[(size_t)m*DINc + h*64 + p0];
    float xa[4] = {xg.x,xg.y,xg.z,xg.w};
    float4 o;
    float* op = (float*)&o;
    #pragma unroll
    for (int j=0;j<4;j++) op[j] = accL[i][j] + Pt*accS[i][j] + Dh*xa[j];
    *(float4*)&y[(size_t)m*DINc + h*64 + p0] = o;
  }
}

// y = rms(y * silu(z)) * gw   (z = zx[:, :DIN]), in-place on y
__global__ __launch_bounds__(256) void k_gate(const float* __restrict__ zx,
    float* __restrict__ y, const float* __restrict__ gw){
  int m = blockIdx.x, tid = threadIdx.x;
  __shared__ float sh[4];
  const float* zr = zx + (size_t)m*DPROJc;
  float* yr = y + (size_t)m*DINc;
  float g[6]; float ss = 0.f;
  #pragma unroll
  for (int k=0;k<6;k++){
    int e = tid + k*256;
    float z = zr[e];
    float v = yr[e] * siluf(z);
    g[k] = v; ss += v*v;
  }
  ss = blk_reduce256(ss, sh);
  float rs = 1.0f / sqrtf(ss/(float)DINc + EPSc);
  #pragma unroll
  for (int k=0;k<6;k++){ int e = tid + k*256; yr[e] = g[k]*rs*gw[e]; }
}

// ---------------- host orchestration ----------------
struct WSP {
  float *x,*res,*xp,*u,*zx,*xh,*Bm,*Cm,*dtsp,*cum,*Sc,*hst,*y,*tmp8,*part,*iwm,*owm;
};

static void run_mixer(hipStream_t st, const WSP& w, const float* u, float* xout,
    int accumOut,
    const float* iw, const float* cw, const float* cb, const float* dtb,
    const float* al, const float* dk, const float* gw, const float* ow,
    const float* iaw, const float* ibw, const float* oaw, const float* obw){
  dim3 gIn((DPROJc + 63)/64, Mtok/128);
  k_gemm<<<gIn, 256, 0, st>>>(u, iw, w.zx, DPROJc, Dm, 1.0f, 0);
  if (iaw){
    k_rank8a<<<Mtok/64, 256, 8*Dm*4, st>>>(u, iaw, w.tmp8, Dm);
    k_rank8b<<<((size_t)Mtok*DPROJc + 255)/256, 256, 0, st>>>(w.tmp8, ibw, w.zx, DPROJc);
  }
  k_conv<<<dim3(Mtok, 7), 256, 0, st>>>(w.zx, cw, cb, dtb, w.xh, w.Bm, w.Cm, w.dtsp);
  k_cumlog<<<Bsz*Hn, 512, 0, st>>>(w.dtsp, al, w.cum);
  k_s1<<<dim3(Bsz*Hn, NCH), 256, 0, st>>>(w.xh, w.Bm, w.cum, w.dtsp, w.Sc);
  k_s2<<<(Bsz*Hn*4096)/256, 256, 0, st>>>(w.Sc, w.cum, w.hst);
  k_s3<<<dim3(Bsz*Hn, NCH), 256, 0, st>>>(w.xh, w.Bm, w.Cm, w.cum, w.dtsp, w.hst, dk, w.y);
  k_gate<<<Mtok, 256, 0, st>>>(w.zx, w.y, gw);
  // out proj: N=768 small -> split-K=8 for parallelism
  dim3 gOut(Dm/64, Mtok/128, 8);
  k_gemm<<<gOut, 256, 0, st>>>(w.y, ow, w.part, Dm, DINc, 1.0f, 0);
  k_ksum<<<((size_t)Mtok*Dm + 255)/256, 256, 0, st>>>(w.part, xout, Dm, 8, accumOut);
  if (oaw){
    k_rank8a<<<Mtok/64, 256, 8*DINc*4, st>>>(w.y, oaw, w.tmp8, DINc);
    k_rank8b<<<((size_t)Mtok*Dm + 255)/256, 256, 0, st>>>(w.tmp8, obw, xout, Dm);
  }
}

extern "C" void kernel_launch(void* const* d_in, const int* in_sizes, int n_in,
                              void* d_out, int out_size, void* d_ws, size_t ws_size,
                              hipStream_t stream){
  const int*   ids        = (const int*)  d_in[0];
  // d_in[1] = n_loops (device scalar) -- statically 3; graph must be fixed anyway.
  const float* emb        = (const float*)d_in[2];
  const float* norm_w     = (const float*)d_in[3];
  const float* in_w       = (const float*)d_in[4];
  const float* conv_w     = (const float*)d_in[5];
  const float* conv_b     = (const float*)d_in[6];
  const float* dt_bias    = (const float*)d_in[7];
  const float* A_log      = (const float*)d_in[8];
  const float* D_skip     = (const float*)d_in[9];
  const float* gnorm_w    = (const float*)d_in[10];
  const float* out_w      = (const float*)d_in[11];
  const float* lora_in_A  = (const float*)d_in[12];
  const float* lora_in_B  = (const float*)d_in[13];
  const float* lora_out_A = (const float*)d_in[14];
  const float* lora_out_B = (const float*)d_in[15];
  const float* core_in_w  = (const float*)d_in[16];
  const float* core_conv_w= (const float*)d_in[17];
  const float* core_conv_b= (const float*)d_in[18];
  const float* core_dtb   = (const float*)d_in[19];
  const float* core_A_log = (const float*)d_in[20];
  const float* core_D     = (const float*)d_in[21];
  const float* core_gw    = (const float*)d_in[22];
  const float* core_out_w = (const float*)d_in[23];
  const float* loop_norm_w= (const float*)d_in[24];
  const float* life_gate  = (const float*)d_in[25];
  const float* norm_f_w   = (const float*)d_in[26];
  const float* lm_head_w  = (const float*)d_in[27];
  (void)in_sizes; (void)n_in; (void)out_size;

  float* p = (float*)d_ws;
  auto alloc = [&](size_t n){ float* q = p; p += n; return q; };
  WSP w;
  w.x    = alloc((size_t)Mtok*Dm);
  w.res  = alloc((size_t)Mtok*Dm);
  w.xp   = alloc((size_t)Mtok*Dm);
  w.u    = alloc((size_t)Mtok*Dm);
  w.zx   = alloc((size_t)Mtok*DPROJc);
  w.xh   = alloc((size_t)Mtok*DINc);
  w.Bm   = alloc((size_t)Mtok*NS);
  w.Cm   = alloc((size_t)Mtok*NS);
  w.dtsp = alloc((size_t)Mtok*Hn);
  w.cum  = alloc((size_t)Bsz*Hn*Tseq);
  w.Sc   = alloc((size_t)Bsz*Hn*NCH*4096);
  w.hst  = alloc((size_t)Bsz*Hn*NCH*4096);
  w.y    = alloc((size_t)Mtok*DINc);
  w.tmp8 = alloc((size_t)Mtok*8);
  w.part = alloc((size_t)8*Mtok*Dm);
  size_t base_floats = (size_t)(p - (float*)d_ws);
  size_t merge_floats = (size_t)LLO * ((size_t)DPROJc*Dm + (size_t)Dm*DINc);
  bool useMerge = ws_size >= (base_floats + merge_floats) * sizeof(float);
  if (useMerge){
    w.iwm = alloc((size_t)LLO*DPROJc*Dm);
    w.owm = alloc((size_t)LLO*Dm*DINc);
    for (int l=0;l<LLO;l++){
      k_lora_merge<<<((size_t)DPROJc*Dm + 255)/256, 256, 0, stream>>>(
          in_w + (size_t)(SPL+l)*DPROJc*Dm, lora_in_B + (size_t)l*DPROJc*8,
          lora_in_A + (size_t)l*8*Dm, w.iwm + (size_t)l*DPROJc*Dm, DPROJc, Dm);
      k_lora_merge<<<((size_t)Dm*DINc + 255)/256, 256, 0, stream>>>(
          out_w + (size_t)(SPL+l)*Dm*DINc, lora_out_B + (size_t)l*Dm*8,
          lora_out_A + (size_t)l*8*DINc, w.owm + (size_t)l*Dm*DINc, Dm, DINc);
    }
  } else { w.iwm = nullptr; w.owm = nullptr; }

  k_embed<<<Mtok, 192, 0, stream>>>(ids, emb, w.x);
  hipMemsetAsync(w.res, 0, (size_t)Mtok*Dm*sizeof(float), stream);

  auto layer = [&](int l, bool lora){
    k_addrms<<<Mtok, 256, 0, stream>>>(w.x, w.res, w.u, norm_w + (size_t)l*Dm);
    const float *iw, *ow, *iaw=nullptr, *ibw=nullptr, *oaw=nullptr, *obw=nullptr;
    if (lora && useMerge){
      int ll = l - SPL;
      iw = w.iwm + (size_t)ll*DPROJc*Dm;
      ow = w.owm + (size_t)ll*Dm*DINc;
    } else {
      iw = in_w + (size_t)l*DPROJc*Dm;
      ow = out_w + (size_t)l*Dm*DINc;
      if (lora){
        int ll = l - SPL;
        iaw = lora_in_A + (size_t)ll*8*Dm;   ibw = lora_in_B + (size_t)ll*DPROJc*8;
        oaw = lora_out_A + (size_t)ll*8*DINc; obw = lora_out_B + (size_t)ll*Dm*8;
      }
    }
    run_mixer(stream, w, w.u, w.x, 0,
        iw, conv_w + (size_t)l*CONVDc*KC, conv_b + (size_t)l*CONVDc,
        dt_bias + (size_t)l*Hn, A_log + (size_t)l*Hn, D_skip + (size_t)l*Hn,
        gnorm_w + (size_t)l*DINc, ow, iaw, ibw, oaw, obw);
  };

  for (int l=0; l<SPL; l++) layer(l, false);
  for (int l=SPL; l<NL; l++) layer(l, true);
  hipMemcpyAsync(w.xp, w.x, (size_t)Mtok*Dm*sizeof(float),
                 hipMemcpyDeviceToDevice, stream);
  for (int i=0;i<NLOOPS;i++){
    k_liferope<<<Mtok, 128, 0, stream>>>(w.x, w.xp, life_gate, (float)i);
    for (int l=SPL; l<NL; l++) layer(l, true);
    run_mixer(stream, w, w.x, w.x, 1,
        core_in_w, core_conv_w, core_conv_b, core_dtb, core_A_log, core_D,
        core_gw, core_out_w, nullptr, nullptr, nullptr, nullptr);
    k_rms<<<Mtok, 256, 0, stream>>>(w.x, w.x, loop_norm_w);
  }
  k_addrms<<<Mtok, 256, 0, stream>>>(w.x, w.res, w.u, norm_f_w);
  dim3 gHead((Vv + 63)/64, Mtok/128);
  k_gemm<<<gHead, 256, 0, stream>>>(w.u, lm_head_w, (float*)d_out, Vv, Dm, 1.0f, 0);
}

// Round 3
// 4690.765 us; speedup vs baseline: 1.6245x; 1.6245x over previous
//
#include <hip/hip_runtime.h>
#include <math.h>

// ---------------- constants (match reference) ----------------
constexpr int Bsz   = 2;
constexpr int Tseq  = 512;
constexpr int Mtok  = Bsz * Tseq;      // 1024 tokens
constexpr int Dm    = 768;
constexpr int DINc  = 1536;
constexpr int Hn    = 24;
constexpr int HD    = 64;
constexpr int NS    = 64;
constexpr int KC    = 4;
constexpr int DPROJc = 2*DINc + 2*NS + Hn;  // 3224
constexpr int CONVDc = DINc + 2*NS;         // 1664
constexpr int NL    = 12;
constexpr int SPL   = 6;
constexpr int LLO   = 6;
constexpr int NCH   = 8;                   // chunks of 64 along T
constexpr int Vv    = 50288;
constexpr float EPSc = 1e-5f;
constexpr int NLOOPS = 3;                  // n_loops (static in setup_inputs)

#define DEVI __device__ __forceinline__

typedef _Float16 f16x8 __attribute__((ext_vector_type(8)));
typedef float    f32x4 __attribute__((ext_vector_type(4)));

DEVI float siluf(float x){ return x / (1.0f + expf(-x)); }
DEVI float softplusf(float x){ return (x > 20.0f) ? x : log1pf(expf(x)); }
DEVI unsigned short f2h(float f){
  union { _Float16 h; unsigned short u; } c;
  c.h = (_Float16)f;                      // RTNE
  return c.u;
}

DEVI float blk_reduce256(float v, float* sh){
  #pragma unroll
  for (int o = 32; o; o >>= 1) v += __shfl_down(v, o);
  int lane = threadIdx.x & 63, w = threadIdx.x >> 6;
  if (lane == 0) sh[w] = v;
  __syncthreads();
  return sh[0] + sh[1] + sh[2] + sh[3];
}

// ---------------- small kernels ----------------
__global__ void k_embed(const int* __restrict__ ids, const float* __restrict__ emb,
                        float* __restrict__ x){
  int m = blockIdx.x;
  int id = ids[m];
  const float4* src = (const float4*)(emb + (size_t)id * Dm);
  float4* dst = (float4*)(x + (size_t)m * Dm);
  int i = threadIdx.x;            // blockDim = 192 = 768/4
  dst[i] = src[i];
}

// f32 -> fp16 convert, 4 elems/thread
__global__ void k_f2h(const float* __restrict__ in, unsigned short* __restrict__ out, int n4){
  int e = blockIdx.x*256 + threadIdx.x;
  if (e >= n4) return;
  float4 v = ((const float4*)in)[e];
  ushort4 o; o.x=f2h(v.x); o.y=f2h(v.y); o.z=f2h(v.z); o.w=f2h(v.w);
  ((ushort4*)out)[e] = o;
}

// res = x + res ; u = rms(res) * w  (f32 and optional fp16 output)
__global__ __launch_bounds__(256) void k_addrms(const float* __restrict__ xin,
    float* __restrict__ res, float* __restrict__ u, unsigned short* __restrict__ ub,
    const float* __restrict__ w){
  int m = blockIdx.x, tid = threadIdx.x;
  __shared__ float sh[4];
  const float* xr = xin + (size_t)m*Dm;
  float* rr = res + (size_t)m*Dm;
  float r[3]; float ss = 0.f;
  #pragma unroll
  for (int k=0;k<3;k++){ int e = tid + k*256; float v = xr[e] + rr[e]; r[k]=v; ss += v*v; }
  ss = blk_reduce256(ss, sh);
  float rs = 1.0f / sqrtf(ss/(float)Dm + EPSc);
  #pragma unroll
  for (int k=0;k<3;k++){
    int e = tid + k*256;
    float v = r[k]*rs*w[e];
    rr[e] = r[k];
    u[(size_t)m*Dm+e] = v;
    if (ub) ub[(size_t)m*Dm+e] = f2h(v);
  }
}

// out = rms(in) * w   (in == out allowed: whole row handled by one block)
__global__ __launch_bounds__(256) void k_rms(const float* __restrict__ xin,
    float* __restrict__ out, const float* __restrict__ w){
  int m = blockIdx.x, tid = threadIdx.x;
  __shared__ float sh[4];
  const float* xr = xin + (size_t)m*Dm;
  float r[3]; float ss = 0.f;
  #pragma unroll
  for (int k=0;k<3;k++){ int e = tid + k*256; float v = xr[e]; r[k]=v; ss += v*v; }
  ss = blk_reduce256(ss, sh);
  float rs = 1.0f / sqrtf(ss/(float)Dm + EPSc);
  #pragma unroll
  for (int k=0;k<3;k++){ int e = tid + k*256; out[(size_t)m*Dm+e] = r[k]*rs*w[e]; }
}

// x = rope(x + gate*xp, loop_i)
__global__ __launch_bounds__(128) void k_liferope(float* __restrict__ x,
    const float* __restrict__ xp, const float* __restrict__ gate, float iF){
  int m = blockIdx.x, tid = threadIdx.x;
  float* xr = x + (size_t)m*Dm;
  const float* pr = xp + (size_t)m*Dm;
  #pragma unroll
  for (int k=0;k<3;k++){
    int j = tid + k*128;               // pair index < 384
    int d0 = 2*j, d1 = d0+1;
    float v0 = xr[d0] + gate[d0]*pr[d0];
    float v1 = xr[d1] + gate[d1]*pr[d1];
    float invf = expf(-9.210340371976184f * ((float)(2*j) * (1.0f/768.0f)));
    float f = iF * invf;
    float cv = cosf(f), sv = sinf(f);
    xr[d0] = v0*cv - v1*sv;
    xr[d1] = v1*cv + v0*sv;
  }
}

// ---------------- f32 GEMM (fallback tier only) ----------------
__global__ __launch_bounds__(256) void k_gemm(const float* __restrict__ A,
    const float* __restrict__ Bw, float* __restrict__ C,
    int Nd, int Kd, float alpha, int accum){
  __shared__ float As[16][132];
  __shared__ float Bs[16][68];
  int n0 = blockIdx.x * 64;
  int m0 = blockIdx.y * 128;
  int KS = gridDim.z;
  int kbeg = blockIdx.z * (Kd / KS);
  int kend = kbeg + Kd / KS;
  int tid = threadIdx.x;
  int tx = tid & 15, ty = tid >> 4;
  int kg = tid & 3;
  int rA = tid >> 2;
  float acc[8][4] = {};
  for (int k0 = kbeg; k0 < kend; k0 += 16){
    #pragma unroll
    for (int p=0;p<2;p++){
      int r = rA + p*64;
      float4 v = *(const float4*)(A + (size_t)(m0 + r)*Kd + k0 + 4*kg);
      As[4*kg+0][r]=v.x; As[4*kg+1][r]=v.y; As[4*kg+2][r]=v.z; As[4*kg+3][r]=v.w;
    }
    {
      int r = rA; int n = n0 + r;
      float4 v = make_float4(0.f,0.f,0.f,0.f);
      if (n < Nd) v = *(const float4*)(Bw + (size_t)n*Kd + k0 + 4*kg);
      Bs[4*kg+0][r]=v.x; Bs[4*kg+1][r]=v.y; Bs[4*kg+2][r]=v.z; Bs[4*kg+3][r]=v.w;
    }
    __syncthreads();
    #pragma unroll
    for (int kk=0; kk<16; kk++){
      float4 a0 = *(const float4*)&As[kk][8*ty];
      float4 a1 = *(const float4*)&As[kk][8*ty+4];
      float4 b  = *(const float4*)&Bs[kk][4*tx];
      float av[8] = {a0.x,a0.y,a0.z,a0.w,a1.x,a1.y,a1.z,a1.w};
      float bv[4] = {b.x,b.y,b.z,b.w};
      #pragma unroll
      for (int i=0;i<8;i++)
        #pragma unroll
        for (int j=0;j<4;j++) acc[i][j] += av[i]*bv[j];
    }
    __syncthreads();
  }
  float* Cb = C;
  if (KS > 1) Cb = C + (size_t)blockIdx.z * (size_t)Mtok * Nd;
  #pragma unroll
  for (int i=0;i<8;i++){
    int m = m0 + 8*ty + i;
    #pragma unroll
    for (int j=0;j<4;j++){
      int n = n0 + 4*tx + j;
      if (n < Nd){
        size_t idx = (size_t)m*Nd + n;
        if (KS > 1) Cb[idx] = acc[i][j];
        else { float v = alpha*acc[i][j]; Cb[idx] = accum ? Cb[idx]+v : v; }
      }
    }
  }
}

// ---------------- fp16 MFMA GEMM: C[M,N] = A[M,K] * W[N,K]^T ----------------
// 128x128 tile, 4 waves (2x2), each wave 64x64 via 4x4 mfma_f32_16x16x32_f16.
// BK=64, reg-staged global->LDS with XOR swizzle (byte ^= (row&7)<<4) applied
// by permuting the per-lane global source column; LDS writes stay linear.
// gridDim.z = KS (split-K): writes raw partials to C + z*Mtok*Nd.
__global__ __launch_bounds__(256) void k_gemm_h(
    const unsigned short* __restrict__ A,
    const unsigned short* __restrict__ Bw,
    float* __restrict__ C, int Nd, int Kd, int accum){
  alignas(16) __shared__ unsigned short lA[128*64];
  alignas(16) __shared__ unsigned short lB[128*64];
  const int tid  = threadIdx.x;
  const int lane = tid & 63;
  const int wv   = tid >> 6;
  const int wm   = wv >> 1, wn = wv & 1;
  const int n0 = blockIdx.x * 128;
  const int m0 = blockIdx.y * 128;
  const int KS = gridDim.z;
  const int kchunk = Kd / KS;         // multiple of 64
  const int kbeg = blockIdx.z * kchunk;
  const int nsteps = kchunk / 64;

  f32x4 acc[4][4] = {};
  uint4 ra[4], rb[4];

  auto load_tile = [&](int k0){
    #pragma unroll
    for (int i=0;i<4;i++){
      int seg = tid + i*256;
      int row = seg >> 3;
      int c8  = (seg & 7) ^ (row & 7);
      ra[i] = *(const uint4*)(A + (size_t)(m0 + row)*Kd + k0 + c8*8);
      int rn = n0 + row; rn = (rn < Nd) ? rn : (Nd - 1);
      rb[i] = *(const uint4*)(Bw + (size_t)rn*Kd + k0 + c8*8);
    }
  };

  load_tile(kbeg);
  for (int t=0; t<nsteps; ++t){
    __syncthreads();
    #pragma unroll
    for (int i=0;i<4;i++){
      *(uint4*)((char*)lA + (tid + i*256)*16) = ra[i];
      *(uint4*)((char*)lB + (tid + i*256)*16) = rb[i];
    }
    if (t+1 < nsteps) load_tile(kbeg + (t+1)*64);
    __syncthreads();
    #pragma unroll
    for (int kk=0; kk<2; kk++){
      f16x8 af[4], bfr[4];
      #pragma unroll
      for (int f=0; f<4; f++){
        int rowa = wm*64 + f*16 + (lane & 15);
        int ba = rowa*128 + ((kk*64 + (lane>>4)*16) ^ ((rowa & 7) << 4));
        af[f] = *(const f16x8*)((const char*)lA + ba);
        int rowb = wn*64 + f*16 + (lane & 15);
        int bb = rowb*128 + ((kk*64 + (lane>>4)*16) ^ ((rowb & 7) << 4));
        bfr[f] = *(const f16x8*)((const char*)lB + bb);
      }
      #pragma unroll
      for (int fm=0; fm<4; fm++)
        #pragma unroll
        for (int fn=0; fn<4; fn++)
          acc[fm][fn] = __builtin_amdgcn_mfma_f32_16x16x32_f16(af[fm], bfr[fn], acc[fm][fn], 0, 0, 0);
    }
  }

  float* Cb = C;
  if (KS > 1) Cb += (size_t)blockIdx.z * ((size_t)Mtok * Nd);
  #pragma unroll
  for (int fm=0; fm<4; fm++){
    int mbase = m0 + wm*64 + fm*16 + ((lane>>4)<<2);
    #pragma unroll
    for (int fn=0; fn<4; fn++){
      int n = n0 + wn*64 + fn*16 + (lane & 15);
      if (n < Nd){
        #pragma unroll
        for (int r=0;r<4;r++){
          size_t idx = (size_t)(mbase + r)*Nd + n;
          float v = acc[fm][fn][r];
          if (KS > 1) Cb[idx] = v;
          else Cb[idx] = accum ? Cb[idx] + v : v;
        }
      }
    }
  }
}

// C = (accum ? C : 0) + sum_s part[s]
__global__ void k_ksum(const float* __restrict__ part, float* __restrict__ C,
                       int Nd, int KS, int accum){
  size_t e = (size_t)blockIdx.x*256 + threadIdx.x;
  size_t tot = (size_t)Mtok*Nd;
  if (e >= tot) return;
  float v = 0.f;
  for (int s=0;s<KS;s++) v += part[(size_t)s*tot + e];
  C[e] = accum ? C[e] + v : v;
}

// Weff = W + 2 * Bl @ Al   (f32 out; fallback tier)
__global__ void k_lora_merge(const float* __restrict__ W, const float* __restrict__ Bl,
    const float* __restrict__ Al, float* __restrict__ out, int Nd, int Kd){
  size_t e = (size_t)blockIdx.x*256 + threadIdx.x;
  if (e >= (size_t)Nd*Kd) return;
  int n = (int)(e / Kd), k = (int)(e % Kd);
  float s = W[e];
  #pragma unroll
  for (int r=0;r<8;r++) s += 2.0f * Bl[n*8+r] * Al[(size_t)r*Kd + k];
  out[e] = s;
}

// Weff = W + 2 * Bl @ Al  -> fp16 out, vectorized x4 along K
__global__ void k_lora_merge_h(const float* __restrict__ W, const float* __restrict__ Bl,
    const float* __restrict__ Al, unsigned short* __restrict__ out, int Nd, int Kd){
  int e4 = blockIdx.x*256 + threadIdx.x;
  int tot4 = Nd*(Kd/4);
  if (e4 >= tot4) return;
  int k4n = Kd/4;
  int n = e4 / k4n, k4 = e4 - n*k4n;
  float4 wv = *(const float4*)(W + (size_t)n*Kd + k4*4);
  float s0=wv.x, s1=wv.y, s2=wv.z, s3=wv.w;
  #pragma unroll
  for (int r=0;r<8;r++){
    float b = 2.0f * Bl[n*8+r];
    float4 a = *(const float4*)(Al + (size_t)r*Kd + k4*4);
    s0 += b*a.x; s1 += b*a.y; s2 += b*a.z; s3 += b*a.w;
  }
  ushort4 o; o.x=f2h(s0); o.y=f2h(s1); o.z=f2h(s2); o.w=f2h(s3);
  ((ushort4*)out)[e4] = o;
}

// fallback rank-8 kernels (f32 tier only)
__global__ __launch_bounds__(256) void k_rank8a(const float* __restrict__ A,
    const float* __restrict__ W8, float* __restrict__ outp, int Kd){
  extern __shared__ float Ws[];
  int tid = threadIdx.x;
  for (int e = tid; e < 8*Kd; e += 256) Ws[e] = W8[e];
  __syncthreads();
  int r = blockIdx.x*64 + (tid >> 2);
  int q = tid & 3;
  const float* Ar = A + (size_t)r*Kd;
  float a0=0.f, a1=0.f;
  for (int k=0;k<Kd;k+=4){
    float4 av = *(const float4*)(Ar + k);
    float4 w0 = *(const float4*)&Ws[q*Kd + k];
    float4 w1 = *(const float4*)&Ws[(q+4)*Kd + k];
    a0 += av.x*w0.x + av.y*w0.y + av.z*w0.z + av.w*w0.w;
    a1 += av.x*w1.x + av.y*w1.y + av.z*w1.z + av.w*w1.w;
  }
  outp[r*8+q] = a0; outp[r*8+q+4] = a1;
}
__global__ void k_rank8b(const float* __restrict__ Tm, const float* __restrict__ W,
    float* __restrict__ C, int Nd){
  size_t gid = (size_t)blockIdx.x*256 + threadIdx.x;
  if (gid >= (size_t)Mtok*Nd) return;
  int m = (int)(gid / Nd), n = (int)(gid % Nd);
  const float* tr = Tm + m*8;
  const float* wr = W + (size_t)n*8;
  float s = 0.f;
  #pragma unroll
  for (int r=0;r<8;r++) s += tr[r]*wr[r];
  C[gid] += 2.0f*s;
}

// ---------------- conv + dt ----------------
__global__ __launch_bounds__(256) void k_conv(const float* __restrict__ zx,
    const float* __restrict__ cw, const float* __restrict__ cb,
    const float* __restrict__ dtb, float* __restrict__ xh, float* __restrict__ Bm,
    float* __restrict__ Cm, float* __restrict__ dtsp){
  int m = blockIdx.x; int b = m >> 9; int t = m & 511;
  int c = blockIdx.y*256 + threadIdx.x;
  if (c < CONVDc){
    float accv = cb[c];
    #pragma unroll
    for (int k=0;k<KC;k++){
      int tt = t + k - (KC-1);
      if (tt >= 0) accv += cw[c*KC + k] * zx[(size_t)(b*Tseq + tt)*DPROJc + DINc + c];
    }
    float v = siluf(accv);
    if (c < DINc)            xh[(size_t)m*DINc + c] = v;
    else if (c < DINc + NS)  Bm[m*NS + (c - DINc)] = v;
    else                     Cm[m*NS + (c - DINc - NS)] = v;
  } else if (c < CONVDc + Hn){
    int h = c - CONVDc;
    float xv = zx[(size_t)m*DPROJc + DINc + CONVDc + h] + dtb[h];
    dtsp[m*Hn + h] = softplusf(xv);
  }
}

// ---------------- SSM scan (SSD chunked, Q=64, NCH=8) ----------------
__global__ __launch_bounds__(512) void k_cumlog(const float* __restrict__ dtsp,
    const float* __restrict__ alog, float* __restrict__ cum){
  int bh = blockIdx.x; int b = bh / Hn, h = bh % Hn;
  int lane = threadIdx.x & 63, w = threadIdx.x >> 6;
  int t = w*64 + lane;
  float Av = -expf(alog[h]);
  float s = dtsp[(b*Tseq + t)*Hn + h] * Av;
  #pragma unroll
  for (int o=1;o<64;o<<=1){ float v = __shfl_up(s, o); if (lane >= o) s += v; }
  cum[bh*Tseq + t] = s;
}

__global__ __launch_bounds__(256) void k_s1(const float* __restrict__ xh,
    const float* __restrict__ Bm, const float* __restrict__ cum,
    const float* __restrict__ dtsp, float* __restrict__ S){
  int bh = blockIdx.x; int b = bh / Hn, h = bh % Hn; int c = blockIdx.y;
  __shared__ float Xc[64][64];
  __shared__ float Bc[64][64];
  __shared__ float wv[64];
  int tid = threadIdx.x;
  int base_m = b*Tseq + c*64;
  for (int e = tid; e < 4096; e += 256){
    int t = e >> 6, p = e & 63;
    Xc[t][p] = xh[(size_t)(base_m + t)*DINc + h*64 + p];
    Bc[t][p] = Bm[(base_m + t)*NS + p];
  }
  if (tid < 64){
    float ce = cum[bh*Tseq + c*64 + 63];
    wv[tid] = expf(ce - cum[bh*Tseq + c*64 + tid]) * dtsp[(base_m + tid)*Hn + h];
  }
  __syncthreads();
  int tx = tid & 15, ty = tid >> 4;
  int nn0 = 4*tx, p0 = 4*ty;
  float acc[4][4] = {};
  #pragma unroll 4
  for (int t=0;t<64;t++){
    float4 xv = *(const float4*)&Xc[t][p0];
    float4 bv = *(const float4*)&Bc[t][nn0];
    float wt = wv[t];
    float wx[4] = {wt*xv.x, wt*xv.y, wt*xv.z, wt*xv.w};
    float bb[4] = {bv.x, bv.y, bv.z, bv.w};
    #pragma unroll
    for (int i=0;i<4;i++)
      #pragma unroll
      for (int j=0;j<4;j++) acc[i][j] += wx[i]*bb[j];
  }
  float* Sb = S + ((size_t)(bh*NCH + c))*4096;
  #pragma unroll
  for (int j=0;j<4;j++){
    float4 o = make_float4(acc[0][j], acc[1][j], acc[2][j], acc[3][j]);
    *(float4*)&Sb[(nn0+j)*64 + p0] = o;
  }
}

__global__ void k_s2(const float* __restrict__ S, const float* __restrict__ cum,
                     float* __restrict__ hst){
  int gid = blockIdx.x*256 + threadIdx.x;
  int bh = gid >> 12; int e = gid & 4095;
  float hv = 0.f;
  #pragma unroll
  for (int c=0;c<NCH;c++){
    size_t idx = ((size_t)(bh*NCH + c))*4096 + e;
    hst[idx] = hv;
    float Ac = expf(cum[bh*Tseq + c*64 + 63]);
    hv = Ac*hv + S[idx];
  }
}

__global__ __launch_bounds__(256) void k_s3(const float* __restrict__ xh,
    const float* __restrict__ Bm, const float* __restrict__ Cm,
    const float* __restrict__ cum, const float* __restrict__ dtsp,
    const float* __restrict__ hst, const float* __restrict__ Dsk,
    float* __restrict__ y){
  int bh = blockIdx.x; int b = bh / Hn, h = bh % Hn; int c = blockIdx.y;
  __shared__ float CcT[64][68];
  __shared__ float BcT[64][68];
  __shared__ float Xc[64][64];
  __shared__ float cumS[64];
  __shared__ float dtS[64];
  int tid = threadIdx.x;
  int base_m = b*Tseq + c*64;
  for (int e = tid; e < 4096; e += 256){
    int t = e >> 6, n = e & 63;
    CcT[n][t] = Cm[(base_m + t)*NS + n];
    BcT[n][t] = Bm[(base_m + t)*NS + n];
    Xc[t][n]  = xh[(size_t)(base_m + t)*DINc + h*64 + n];
  }
  if (tid < 64){
    cumS[tid] = cum[bh*Tseq + c*64 + tid];
    dtS[tid]  = dtsp[(base_m + tid)*Hn + h];
  }
  __syncthreads();
  int tx = tid & 15, ty = tid >> 4;
  int t0 = 4*tx, s0 = 4*ty;
  float G[4][4] = {};
  #pragma unroll 4
  for (int n=0;n<64;n++){
    float4 cv = *(const float4*)&CcT[n][t0];
    float4 bv = *(const float4*)&BcT[n][s0];
    float ca[4]={cv.x,cv.y,cv.z,cv.w}, ba[4]={bv.x,bv.y,bv.z,bv.w};
    #pragma unroll
    for (int i=0;i<4;i++)
      #pragma unroll
      for (int j=0;j<4;j++) G[i][j] += ca[i]*ba[j];
  }
  __syncthreads();
  #pragma unroll
  for (int j=0;j<4;j++){
    int s = s0 + j;
    float4 o;
    float* op = (float*)&o;
    #pragma unroll
    for (int i=0;i<4;i++){
      int t = t0 + i;
      op[i] = (s <= t) ? expf(cumS[t] - cumS[s]) * dtS[s] * G[i][j] : 0.f;
    }
    *(float4*)&BcT[s][t0] = o;
  }
  __syncthreads();
  int p0 = s0;
  float accL[4][4] = {};
  #pragma unroll 4
  for (int s=0;s<64;s++){
    float4 mv = *(const float4*)&BcT[s][t0];
    float4 xv = *(const float4*)&Xc[s][p0];
    float ma[4]={mv.x,mv.y,mv.z,mv.w}, xa[4]={xv.x,xv.y,xv.z,xv.w};
    #pragma unroll
    for (int i=0;i<4;i++)
      #pragma unroll
      for (int j=0;j<4;j++) accL[i][j] += ma[i]*xa[j];
  }
  __syncthreads();
  {
    const float* hb = hst + ((size_t)(bh*NCH + c))*4096;
    for (int e = tid; e < 4096; e += 256) ((float*)Xc)[e] = hb[e];
  }
  __syncthreads();
  float accS[4][4] = {};
  #pragma unroll 4
  for (int n=0;n<64;n++){
    float4 cv = *(const float4*)&CcT[n][t0];
    float4 hv = *(const float4*)&((float*)Xc)[n*64 + p0];
    float ca[4]={cv.x,cv.y,cv.z,cv.w}, ha[4]={hv.x,hv.y,hv.z,hv.w};
    #pragma unroll
    for (int i=0;i<4;i++)
      #pragma unroll
      for (int j=0;j<4;j++) accS[i][j] += ca[i]*ha[j];
  }
  float Dh = Dsk[h];
  #pragma unroll
  for (int i=0;i<4;i++){
    int t = t0 + i;
    int m = base_m + t;
    float Pt = expf(cumS[t]);
    float4 xg = *(const float4*)&xh[(size_t)m*DINc + h*64 + p0];
    float xa[4] = {xg.x,xg.y,xg.z,xg.w};
    float4 o;
    float* op = (float*)&o;
    #pragma unroll
    for (int j=0;j<4;j++) op[j] = accL[i][j] + Pt*accS[i][j] + Dh*xa[j];
    *(float4*)&y[(size_t)m*DINc + h*64 + p0] = o;
  }
}

// y = rms(y * silu(z)) * gw ; writes f32 in-place + optional fp16
__global__ __launch_bounds__(256) void k_gate(const float* __restrict__ zx,
    float* __restrict__ y, unsigned short* __restrict__ yb,
    const float* __restrict__ gw){
  int m = blockIdx.x, tid = threadIdx.x;
  __shared__ float sh[4];
  const float* zr = zx + (size_t)m*DPROJc;
  float* yr = y + (size_t)m*DINc;
  float g[6]; float ss = 0.f;
  #pragma unroll
  for (int k=0;k<6;k++){
    int e = tid + k*256;
    float z = zr[e];
    float v = yr[e] * siluf(z);
    g[k] = v; ss += v*v;
  }
  ss = blk_reduce256(ss, sh);
  float rs = 1.0f / sqrtf(ss/(float)DINc + EPSc);
  #pragma unroll
  for (int k=0;k<6;k++){
    int e = tid + k*256;
    float v = g[k]*rs*gw[e];
    yr[e] = v;
    if (yb) yb[(size_t)m*DINc + e] = f2h(v);
  }
}

// ---------------- host orchestration ----------------
struct WSP {
  float *x,*res,*xp,*u,*zx,*xh,*Bm,*Cm,*dtsp,*cum,*Sc,*hst,*y,*tmp8,*part,*iwm,*owm;
  unsigned short *ub,*yb,*wib,*wob,*whb;   // fp16 tier
};

// ---- fp16-tier mixer ----
static void run_mixer_h(hipStream_t st, const WSP& w, const unsigned short* ub_in,
    float* xout, int accumOut,
    const unsigned short* iw, const float* cw, const float* cb, const float* dtb,
    const float* al, const float* dk, const float* gw, const unsigned short* ow){
  dim3 gIn((DPROJc + 127)/128, Mtok/128, 1);
  k_gemm_h<<<gIn, 256, 0, st>>>(ub_in, iw, w.zx, DPROJc, Dm, 0);
  k_conv<<<dim3(Mtok, 7), 256, 0, st>>>(w.zx, cw, cb, dtb, w.xh, w.Bm, w.Cm, w.dtsp);
  k_cumlog<<<Bsz*Hn, 512, 0, st>>>(w.dtsp, al, w.cum);
  k_s1<<<dim3(Bsz*Hn, NCH), 256, 0, st>>>(w.xh, w.Bm, w.cum, w.dtsp, w.Sc);
  k_s2<<<(Bsz*Hn*4096)/256, 256, 0, st>>>(w.Sc, w.cum, w.hst);
  k_s3<<<dim3(Bsz*Hn, NCH), 256, 0, st>>>(w.xh, w.Bm, w.Cm, w.cum, w.dtsp, w.hst, dk, w.y);
  k_gate<<<Mtok, 256, 0, st>>>(w.zx, w.y, w.yb, gw);
  dim3 gOut(Dm/128, Mtok/128, 4);      // split-K=4
  k_gemm_h<<<gOut, 256, 0, st>>>(w.yb, ow, w.part, Dm, DINc, 0);
  k_ksum<<<((size_t)Mtok*Dm + 255)/256, 256, 0, st>>>(w.part, xout, Dm, 4, accumOut);
}

// ---- f32 fallback mixer (round-1 path) ----
static void run_mixer(hipStream_t st, const WSP& w, const float* u, float* xout,
    int accumOut,
    const float* iw, const float* cw, const float* cb, const float* dtb,
    const float* al, const float* dk, const float* gw, const float* ow,
    const float* iaw, const float* ibw, const float* oaw, const float* obw){
  dim3 gIn((DPROJc + 63)/64, Mtok/128);
  k_gemm<<<gIn, 256, 0, st>>>(u, iw, w.zx, DPROJc, Dm, 1.0f, 0);
  if (iaw){
    k_rank8a<<<Mtok/64, 256, 8*Dm*4, st>>>(u, iaw, w.tmp8, Dm);
    k_rank8b<<<((size_t)Mtok*DPROJc + 255)/256, 256, 0, st>>>(w.tmp8, ibw, w.zx, DPROJc);
  }
  k_conv<<<dim3(Mtok, 7), 256, 0, st>>>(w.zx, cw, cb, dtb, w.xh, w.Bm, w.Cm, w.dtsp);
  k_cumlog<<<Bsz*Hn, 512, 0, st>>>(w.dtsp, al, w.cum);
  k_s1<<<dim3(Bsz*Hn, NCH), 256, 0, st>>>(w.xh, w.Bm, w.cum, w.dtsp, w.Sc);
  k_s2<<<(Bsz*Hn*4096)/256, 256, 0, st>>>(w.Sc, w.cum, w.hst);
  k_s3<<<dim3(Bsz*Hn, NCH), 256, 0, st>>>(w.xh, w.Bm, w.Cm, w.cum, w.dtsp, w.hst, dk, w.y);
  k_gate<<<Mtok, 256, 0, st>>>(w.zx, w.y, nullptr, gw);
  dim3 gOut(Dm/64, Mtok/128, 8);
  k_gemm<<<gOut, 256, 0, st>>>(w.y, ow, w.part, Dm, DINc, 1.0f, 0);
  k_ksum<<<((size_t)Mtok*Dm + 255)/256, 256, 0, st>>>(w.part, xout, Dm, 8, accumOut);
  if (oaw){
    k_rank8a<<<Mtok/64, 256, 8*DINc*4, st>>>(w.y, oaw, w.tmp8, DINc);
    k_rank8b<<<((size_t)Mtok*Dm + 255)/256, 256, 0, st>>>(w.tmp8, obw, xout, Dm);
  }
}

extern "C" void kernel_launch(void* const* d_in, const int* in_sizes, int n_in,
                              void* d_out, int out_size, void* d_ws, size_t ws_size,
                              hipStream_t stream){
  const int*   ids        = (const int*)  d_in[0];
  // d_in[1] = n_loops (device scalar) -- statically 3; graph must be fixed anyway.
  const float* emb        = (const float*)d_in[2];
  const float* norm_w     = (const float*)d_in[3];
  const float* in_w       = (const float*)d_in[4];
  const float* conv_w     = (const float*)d_in[5];
  const float* conv_b     = (const float*)d_in[6];
  const float* dt_bias    = (const float*)d_in[7];
  const float* A_log      = (const float*)d_in[8];
  const float* D_skip     = (const float*)d_in[9];
  const float* gnorm_w    = (const float*)d_in[10];
  const float* out_w      = (const float*)d_in[11];
  const float* lora_in_A  = (const float*)d_in[12];
  const float* lora_in_B  = (const float*)d_in[13];
  const float* lora_out_A = (const float*)d_in[14];
  const float* lora_out_B = (const float*)d_in[15];
  const float* core_in_w  = (const float*)d_in[16];
  const float* core_conv_w= (const float*)d_in[17];
  const float* core_conv_b= (const float*)d_in[18];
  const float* core_dtb   = (const float*)d_in[19];
  const float* core_A_log = (const float*)d_in[20];
  const float* core_D     = (const float*)d_in[21];
  const float* core_gw    = (const float*)d_in[22];
  const float* core_out_w = (const float*)d_in[23];
  const float* loop_norm_w= (const float*)d_in[24];
  const float* life_gate  = (const float*)d_in[25];
  const float* norm_f_w   = (const float*)d_in[26];
  const float* lm_head_w  = (const float*)d_in[27];
  (void)in_sizes; (void)n_in; (void)out_size;

  char* pb = (char*)d_ws;
  auto balloc = [&](size_t bytes){
    char* q = pb; pb += (bytes + 255) & ~(size_t)255; return q;
  };
  WSP w;
  w.x    = (float*)balloc((size_t)Mtok*Dm*4);
  w.res  = (float*)balloc((size_t)Mtok*Dm*4);
  w.xp   = (float*)balloc((size_t)Mtok*Dm*4);
  w.u    = (float*)balloc((size_t)Mtok*Dm*4);
  w.zx   = (float*)balloc((size_t)Mtok*DPROJc*4);
  w.xh   = (float*)balloc((size_t)Mtok*DINc*4);
  w.Bm   = (float*)balloc((size_t)Mtok*NS*4);
  w.Cm   = (float*)balloc((size_t)Mtok*NS*4);
  w.dtsp = (float*)balloc((size_t)Mtok*Hn*4);
  w.cum  = (float*)balloc((size_t)Bsz*Hn*Tseq*4);
  w.Sc   = (float*)balloc((size_t)Bsz*Hn*NCH*4096*4);
  w.hst  = (float*)balloc((size_t)Bsz*Hn*NCH*4096*4);
  w.y    = (float*)balloc((size_t)Mtok*DINc*4);
  w.tmp8 = (float*)balloc((size_t)Mtok*8*4);
  w.part = (float*)balloc((size_t)8*Mtok*Dm*4);

  const size_t IWN = (size_t)DPROJc*Dm;      // 2,476,032
  const size_t OWN = (size_t)Dm*DINc;        // 1,179,648
  const size_t HWN = (size_t)Vv*Dm;          // 38,621,184
  size_t h_bytes = ((size_t)Mtok*Dm + (size_t)Mtok*DINc + 13*IWN + 13*OWN + HWN) * 2
                    + 8*256;
  size_t used = (size_t)(pb - (char*)d_ws);
  bool hTier = (used + h_bytes) <= ws_size;

  if (hTier){
    w.ub  = (unsigned short*)balloc((size_t)Mtok*Dm*2);
    w.yb  = (unsigned short*)balloc((size_t)Mtok*DINc*2);
    w.wib = (unsigned short*)balloc(13*IWN*2);
    w.wob = (unsigned short*)balloc(13*OWN*2);
    w.whb = (unsigned short*)balloc(HWN*2);
    // ---- one-time (per launch) weight conversion / LoRA merge ----
    k_f2h<<<(6*IWN/4 + 255)/256, 256, 0, stream>>>(in_w,  w.wib, (int)(6*IWN/4));
    k_f2h<<<(6*OWN/4 + 255)/256, 256, 0, stream>>>(out_w, w.wob, (int)(6*OWN/4));
    for (int l=0;l<LLO;l++){
      k_lora_merge_h<<<(IWN/4 + 255)/256, 256, 0, stream>>>(
          in_w + (size_t)(SPL+l)*IWN, lora_in_B + (size_t)l*DPROJc*8,
          lora_in_A + (size_t)l*8*Dm, w.wib + (SPL+l)*IWN, DPROJc, Dm);
      k_lora_merge_h<<<(OWN/4 + 255)/256, 256, 0, stream>>>(
          out_w + (size_t)(SPL+l)*OWN, lora_out_B + (size_t)l*Dm*8,
          lora_out_A + (size_t)l*8*DINc, w.wob + (SPL+l)*OWN, Dm, DINc);
    }
    k_f2h<<<(IWN/4 + 255)/256, 256, 0, stream>>>(core_in_w,  w.wib + 12*IWN, (int)(IWN/4));
    k_f2h<<<(OWN/4 + 255)/256, 256, 0, stream>>>(core_out_w, w.wob + 12*OWN, (int)(OWN/4));
    k_f2h<<<(HWN/4 + 255)/256, 256, 0, stream>>>(lm_head_w, w.whb, (int)(HWN/4));
    w.iwm = nullptr; w.owm = nullptr;
  } else {
    w.ub = nullptr; w.yb = nullptr; w.wib = nullptr; w.wob = nullptr; w.whb = nullptr;
    size_t merge_bytes = (size_t)LLO * (IWN + OWN) * 4;
    bool useMerge = (used + merge_bytes) <= ws_size;
    if (useMerge){
      w.iwm = (float*)balloc((size_t)LLO*IWN*4);
      w.owm = (float*)balloc((size_t)LLO*OWN*4);
      for (int l=0;l<LLO;l++){
        k_lora_merge<<<(IWN + 255)/256, 256, 0, stream>>>(
            in_w + (size_t)(SPL+l)*IWN, lora_in_B + (size_t)l*DPROJc*8,
            lora_in_A + (size_t)l*8*Dm, w.iwm + (size_t)l*IWN, DPROJc, Dm);
        k_lora_merge<<<(OWN + 255)/256, 256, 0, stream>>>(
            out_w + (size_t)(SPL+l)*OWN, lora_out_B + (size_t)l*Dm*8,
            lora_out_A + (size_t)l*8*DINc, w.owm + (size_t)l*OWN, Dm, DINc);
      }
    } else { w.iwm = nullptr; w.owm = nullptr; }
  }

  k_embed<<<Mtok, 192, 0, stream>>>(ids, emb, w.x);
  hipMemsetAsync(w.res, 0, (size_t)Mtok*Dm*sizeof(float), stream);

  auto layer = [&](int l, bool lora){
    k_addrms<<<Mtok, 256, 0, stream>>>(w.x, w.res, w.u, w.ub, norm_w + (size_t)l*Dm);
    if (hTier){
      run_mixer_h(stream, w, w.ub, w.x, 0,
          w.wib + (size_t)l*IWN, conv_w + (size_t)l*CONVDc*KC, conv_b + (size_t)l*CONVDc,
          dt_bias + (size_t)l*Hn, A_log + (size_t)l*Hn, D_skip + (size_t)l*Hn,
          gnorm_w + (size_t)l*DINc, w.wob + (size_t)l*OWN);
      return;
    }
    const float *iw, *ow, *iaw=nullptr, *ibw=nullptr, *oaw=nullptr, *obw=nullptr;
    if (lora && w.iwm){
      int ll = l - SPL;
      iw = w.iwm + (size_t)ll*IWN;
      ow = w.owm + (size_t)ll*OWN;
    } else {
      iw = in_w + (size_t)l*IWN;
      ow = out_w + (size_t)l*OWN;
      if (lora){
        int ll = l - SPL;
        iaw = lora_in_A + (size_t)ll*8*Dm;    ibw = lora_in_B + (size_t)ll*DPROJc*8;
        oaw = lora_out_A + (size_t)ll*8*DINc; obw = lora_out_B + (size_t)ll*Dm*8;
      }
    }
    run_mixer(stream, w, w.u, w.x, 0,
        iw, conv_w + (size_t)l*CONVDc*KC, conv_b + (size_t)l*CONVDc,
        dt_bias + (size_t)l*Hn, A_log + (size_t)l*Hn, D_skip + (size_t)l*Hn,
        gnorm_w + (size_t)l*DINc, ow, iaw, ibw, oaw, obw);
  };

  auto core_mixer = [&](){
    if (hTier){
      k_f2h<<<((size_t)Mtok*Dm/4 + 255)/256, 256, 0, stream>>>(w.x, w.ub, Mtok*Dm/4);
      run_mixer_h(stream, w, w.ub, w.x, 1,
          w.wib + 12*IWN, core_conv_w, core_conv_b, core_dtb, core_A_log, core_D,
          core_gw, w.wob + 12*OWN);
    } else {
      run_mixer(stream, w, w.x, w.x, 1,
          core_in_w, core_conv_w, core_conv_b, core_dtb, core_A_log, core_D,
          core_gw, core_out_w, nullptr, nullptr, nullptr, nullptr);
    }
  };

  for (int l=0; l<SPL; l++) layer(l, false);
  for (int l=SPL; l<NL; l++) layer(l, true);
  hipMemcpyAsync(w.xp, w.x, (size_t)Mtok*Dm*sizeof(float),
                 hipMemcpyDeviceToDevice, stream);
  for (int i=0;i<NLOOPS;i++){
    k_liferope<<<Mtok, 128, 0, stream>>>(w.x, w.xp, life_gate, (float)i);
    for (int l=SPL; l<NL; l++) layer(l, true);
    core_mixer();
    k_rms<<<Mtok, 256, 0, stream>>>(w.x, w.x, loop_norm_w);
  }
  k_addrms<<<Mtok, 256, 0, stream>>>(w.x, w.res, w.u, w.ub, norm_f_w);
  if (hTier){
    dim3 gHead((Vv + 127)/128, Mtok/128, 1);
    k_gemm_h<<<gHead, 256, 0, stream>>>(w.ub, w.whb, (float*)d_out, Vv, Dm, 0);
  } else {
    dim3 gHead((Vv + 63)/64, Mtok/128);
    k_gemm<<<gHead, 256, 0, stream>>>(w.u, lm_head_w, (float*)d_out, Vv, Dm, 1.0f, 0);
  }
}

// Round 4
// 4481.103 us; speedup vs baseline: 1.7005x; 1.0468x over previous
//
#include <hip/hip_runtime.h>
#include <math.h>

// ---------------- constants (match reference) ----------------
constexpr int Bsz   = 2;
constexpr int Tseq  = 512;
constexpr int Mtok  = Bsz * Tseq;      // 1024 tokens
constexpr int Dm    = 768;
constexpr int DINc  = 1536;
constexpr int Hn    = 24;
constexpr int HD    = 64;
constexpr int NS    = 64;
constexpr int KC    = 4;
constexpr int DPROJc = 2*DINc + 2*NS + Hn;  // 3224
constexpr int CONVDc = DINc + 2*NS;         // 1664
constexpr int NL    = 12;
constexpr int SPL   = 6;
constexpr int LLO   = 6;
constexpr int NCH   = 8;                   // chunks of 64 along T
constexpr int Vv    = 50288;
constexpr float EPSc = 1e-5f;
constexpr int NLOOPS = 3;                  // n_loops (static in setup_inputs)

#define DEVI __device__ __forceinline__

typedef _Float16 f16x8 __attribute__((ext_vector_type(8)));
typedef float    f32x4 __attribute__((ext_vector_type(4)));

DEVI float siluf(float x){ return x / (1.0f + expf(-x)); }
DEVI float softplusf(float x){ return (x > 20.0f) ? x : log1pf(expf(x)); }
DEVI unsigned short f2h(float f){
  union { _Float16 h; unsigned short u; } c;
  c.h = (_Float16)f;                      // RTNE
  return c.u;
}

DEVI float blk_reduce256(float v, float* sh){
  #pragma unroll
  for (int o = 32; o; o >>= 1) v += __shfl_down(v, o);
  int lane = threadIdx.x & 63, w = threadIdx.x >> 6;
  if (lane == 0) sh[w] = v;
  __syncthreads();
  return sh[0] + sh[1] + sh[2] + sh[3];
}

// ---------------- small kernels ----------------
__global__ void k_embed(const int* __restrict__ ids, const float* __restrict__ emb,
                        float* __restrict__ x){
  int m = blockIdx.x;
  int id = ids[m];
  const float4* src = (const float4*)(emb + (size_t)id * Dm);
  float4* dst = (float4*)(x + (size_t)m * Dm);
  int i = threadIdx.x;            // blockDim = 192 = 768/4
  dst[i] = src[i];
}

// f32 -> fp16 convert, 4 elems/thread
__global__ void k_f2h(const float* __restrict__ in, unsigned short* __restrict__ out, int n4){
  int e = blockIdx.x*256 + threadIdx.x;
  if (e >= n4) return;
  float4 v = ((const float4*)in)[e];
  ushort4 o; o.x=f2h(v.x); o.y=f2h(v.y); o.z=f2h(v.z); o.w=f2h(v.w);
  ((ushort4*)out)[e] = o;
}

// res = x + res ; u = rms(res) * w  (f32 and optional fp16 output)
__global__ __launch_bounds__(256) void k_addrms(const float* __restrict__ xin,
    float* __restrict__ res, float* __restrict__ u, unsigned short* __restrict__ ub,
    const float* __restrict__ w){
  int m = blockIdx.x, tid = threadIdx.x;
  __shared__ float sh[4];
  const float* xr = xin + (size_t)m*Dm;
  float* rr = res + (size_t)m*Dm;
  float r[3]; float ss = 0.f;
  #pragma unroll
  for (int k=0;k<3;k++){ int e = tid + k*256; float v = xr[e] + rr[e]; r[k]=v; ss += v*v; }
  ss = blk_reduce256(ss, sh);
  float rs = 1.0f / sqrtf(ss/(float)Dm + EPSc);
  #pragma unroll
  for (int k=0;k<3;k++){
    int e = tid + k*256;
    float v = r[k]*rs*w[e];
    rr[e] = r[k];
    u[(size_t)m*Dm+e] = v;
    if (ub) ub[(size_t)m*Dm+e] = f2h(v);
  }
}

// res = (sum of 4 split-K partials) + res ; u = rms(res)*w (fused k_ksum+addrms)
__global__ __launch_bounds__(256) void k_addrms_p(const float* __restrict__ part,
    float* __restrict__ res, float* __restrict__ u, unsigned short* __restrict__ ub,
    const float* __restrict__ w){
  int m = blockIdx.x, tid = threadIdx.x;
  __shared__ float sh[4];
  const size_t tot = (size_t)Mtok*Dm;
  float* rr = res + (size_t)m*Dm;
  float r[3]; float ss = 0.f;
  #pragma unroll
  for (int k=0;k<3;k++){
    int e = tid + k*256;
    size_t idx = (size_t)m*Dm + e;
    float v = rr[e] + part[idx] + part[tot+idx] + part[2*tot+idx] + part[3*tot+idx];
    r[k]=v; ss += v*v;
  }
  ss = blk_reduce256(ss, sh);
  float rs = 1.0f / sqrtf(ss/(float)Dm + EPSc);
  #pragma unroll
  for (int k=0;k<3;k++){
    int e = tid + k*256;
    float v = r[k]*rs*w[e];
    rr[e] = r[k];
    u[(size_t)m*Dm+e] = v;
    if (ub) ub[(size_t)m*Dm+e] = f2h(v);
  }
}

// x = sum parts ; xp = x   (prompt-end snapshot)
__global__ void k_sum_xp(const float* __restrict__ part, float* __restrict__ x,
                         float* __restrict__ xp){
  size_t e = (size_t)blockIdx.x*256 + threadIdx.x;
  const size_t tot = (size_t)Mtok*Dm;
  if (e >= tot) return;
  float v = part[e] + part[tot+e] + part[2*tot+e] + part[3*tot+e];
  x[e] = v; xp[e] = v;
}

// x = sum parts ; ub = fp16(x)   (core-mixer input)
__global__ void k_f2h_sum(const float* __restrict__ part, float* __restrict__ x,
                          unsigned short* __restrict__ ub){
  size_t e = (size_t)blockIdx.x*256 + threadIdx.x;
  const size_t tot = (size_t)Mtok*Dm;
  if (e >= tot) return;
  float v = part[e] + part[tot+e] + part[2*tot+e] + part[3*tot+e];
  x[e] = v; ub[e] = f2h(v);
}

// x = rms(x + sum parts) * w   (loop norm, in-place)
__global__ __launch_bounds__(256) void k_rms_p(const float* __restrict__ part,
    float* __restrict__ x, const float* __restrict__ w){
  int m = blockIdx.x, tid = threadIdx.x;
  __shared__ float sh[4];
  const size_t tot = (size_t)Mtok*Dm;
  float* xr = x + (size_t)m*Dm;
  float r[3]; float ss = 0.f;
  #pragma unroll
  for (int k=0;k<3;k++){
    int e = tid + k*256;
    size_t idx = (size_t)m*Dm + e;
    float v = xr[e] + part[idx] + part[tot+idx] + part[2*tot+idx] + part[3*tot+idx];
    r[k]=v; ss += v*v;
  }
  ss = blk_reduce256(ss, sh);
  float rs = 1.0f / sqrtf(ss/(float)Dm + EPSc);
  #pragma unroll
  for (int k=0;k<3;k++){ int e = tid + k*256; xr[e] = r[k]*rs*w[e]; }
}

// out = rms(in) * w   (f32 fallback tier)
__global__ __launch_bounds__(256) void k_rms(const float* __restrict__ xin,
    float* __restrict__ out, const float* __restrict__ w){
  int m = blockIdx.x, tid = threadIdx.x;
  __shared__ float sh[4];
  const float* xr = xin + (size_t)m*Dm;
  float r[3]; float ss = 0.f;
  #pragma unroll
  for (int k=0;k<3;k++){ int e = tid + k*256; float v = xr[e]; r[k]=v; ss += v*v; }
  ss = blk_reduce256(ss, sh);
  float rs = 1.0f / sqrtf(ss/(float)Dm + EPSc);
  #pragma unroll
  for (int k=0;k<3;k++){ int e = tid + k*256; out[(size_t)m*Dm+e] = r[k]*rs*w[e]; }
}

// x = rope(x + gate*xp, loop_i)
__global__ __launch_bounds__(128) void k_liferope(float* __restrict__ x,
    const float* __restrict__ xp, const float* __restrict__ gate, float iF){
  int m = blockIdx.x, tid = threadIdx.x;
  float* xr = x + (size_t)m*Dm;
  const float* pr = xp + (size_t)m*Dm;
  #pragma unroll
  for (int k=0;k<3;k++){
    int j = tid + k*128;               // pair index < 384
    int d0 = 2*j, d1 = d0+1;
    float v0 = xr[d0] + gate[d0]*pr[d0];
    float v1 = xr[d1] + gate[d1]*pr[d1];
    float invf = expf(-9.210340371976184f * ((float)(2*j) * (1.0f/768.0f)));
    float f = iF * invf;
    float cv = cosf(f), sv = sinf(f);
    xr[d0] = v0*cv - v1*sv;
    xr[d1] = v1*cv + v0*sv;
  }
}

// ---------------- f32 GEMM (fallback tier only) ----------------
__global__ __launch_bounds__(256) void k_gemm(const float* __restrict__ A,
    const float* __restrict__ Bw, float* __restrict__ C,
    int Nd, int Kd, float alpha, int accum){
  __shared__ float As[16][132];
  __shared__ float Bs[16][68];
  int n0 = blockIdx.x * 64;
  int m0 = blockIdx.y * 128;
  int KS = gridDim.z;
  int kbeg = blockIdx.z * (Kd / KS);
  int kend = kbeg + Kd / KS;
  int tid = threadIdx.x;
  int tx = tid & 15, ty = tid >> 4;
  int kg = tid & 3;
  int rA = tid >> 2;
  float acc[8][4] = {};
  for (int k0 = kbeg; k0 < kend; k0 += 16){
    #pragma unroll
    for (int p=0;p<2;p++){
      int r = rA + p*64;
      float4 v = *(const float4*)(A + (size_t)(m0 + r)*Kd + k0 + 4*kg);
      As[4*kg+0][r]=v.x; As[4*kg+1][r]=v.y; As[4*kg+2][r]=v.z; As[4*kg+3][r]=v.w;
    }
    {
      int r = rA; int n = n0 + r;
      float4 v = make_float4(0.f,0.f,0.f,0.f);
      if (n < Nd) v = *(const float4*)(Bw + (size_t)n*Kd + k0 + 4*kg);
      Bs[4*kg+0][r]=v.x; Bs[4*kg+1][r]=v.y; Bs[4*kg+2][r]=v.z; Bs[4*kg+3][r]=v.w;
    }
    __syncthreads();
    #pragma unroll
    for (int kk=0; kk<16; kk++){
      float4 a0 = *(const float4*)&As[kk][8*ty];
      float4 a1 = *(const float4*)&As[kk][8*ty+4];
      float4 b  = *(const float4*)&Bs[kk][4*tx];
      float av[8] = {a0.x,a0.y,a0.z,a0.w,a1.x,a1.y,a1.z,a1.w};
      float bv[4] = {b.x,b.y,b.z,b.w};
      #pragma unroll
      for (int i=0;i<8;i++)
        #pragma unroll
        for (int j=0;j<4;j++) acc[i][j] += av[i]*bv[j];
    }
    __syncthreads();
  }
  float* Cb = C;
  if (KS > 1) Cb = C + (size_t)blockIdx.z * (size_t)Mtok * Nd;
  #pragma unroll
  for (int i=0;i<8;i++){
    int m = m0 + 8*ty + i;
    #pragma unroll
    for (int j=0;j<4;j++){
      int n = n0 + 4*tx + j;
      if (n < Nd){
        size_t idx = (size_t)m*Nd + n;
        if (KS > 1) Cb[idx] = acc[i][j];
        else { float v = alpha*acc[i][j]; Cb[idx] = accum ? Cb[idx]+v : v; }
      }
    }
  }
}

// ---------------- fp16 MFMA GEMM: C[M,N] = A[M,K] * W[N,K]^T ----------------
// 128x128 tile, 4 waves (2x2), each wave 64x64 via 4x4 mfma_f32_16x16x32_f16.
// BK=64, reg-staged global->LDS with XOR swizzle (byte ^= (row&7)<<4) applied
// by permuting the per-lane global source column; LDS writes stay linear.
// gridDim.z = KS (split-K): writes raw partials to C + z*Mtok*Nd.
__global__ __launch_bounds__(256) void k_gemm_h(
    const unsigned short* __restrict__ A,
    const unsigned short* __restrict__ Bw,
    float* __restrict__ C, int Nd, int Kd, int accum){
  alignas(16) __shared__ unsigned short lA[128*64];
  alignas(16) __shared__ unsigned short lB[128*64];
  const int tid  = threadIdx.x;
  const int lane = tid & 63;
  const int wv   = tid >> 6;
  const int wm   = wv >> 1, wn = wv & 1;
  const int n0 = blockIdx.x * 128;
  const int m0 = blockIdx.y * 128;
  const int KS = gridDim.z;
  const int kchunk = Kd / KS;         // multiple of 64
  const int kbeg = blockIdx.z * kchunk;
  const int nsteps = kchunk / 64;

  f32x4 acc[4][4] = {};
  uint4 ra[4], rb[4];

  auto load_tile = [&](int k0){
    #pragma unroll
    for (int i=0;i<4;i++){
      int seg = tid + i*256;
      int row = seg >> 3;
      int c8  = (seg & 7) ^ (row & 7);
      ra[i] = *(const uint4*)(A + (size_t)(m0 + row)*Kd + k0 + c8*8);
      int rn = n0 + row; rn = (rn < Nd) ? rn : (Nd - 1);
      rb[i] = *(const uint4*)(Bw + (size_t)rn*Kd + k0 + c8*8);
    }
  };

  load_tile(kbeg);
  for (int t=0; t<nsteps; ++t){
    __syncthreads();
    #pragma unroll
    for (int i=0;i<4;i++){
      *(uint4*)((char*)lA + (tid + i*256)*16) = ra[i];
      *(uint4*)((char*)lB + (tid + i*256)*16) = rb[i];
    }
    if (t+1 < nsteps) load_tile(kbeg + (t+1)*64);
    __syncthreads();
    #pragma unroll
    for (int kk=0; kk<2; kk++){
      f16x8 af[4], bfr[4];
      #pragma unroll
      for (int f=0; f<4; f++){
        int rowa = wm*64 + f*16 + (lane & 15);
        int ba = rowa*128 + ((kk*64 + (lane>>4)*16) ^ ((rowa & 7) << 4));
        af[f] = *(const f16x8*)((const char*)lA + ba);
        int rowb = wn*64 + f*16 + (lane & 15);
        int bb = rowb*128 + ((kk*64 + (lane>>4)*16) ^ ((rowb & 7) << 4));
        bfr[f] = *(const f16x8*)((const char*)lB + bb);
      }
      #pragma unroll
      for (int fm=0; fm<4; fm++)
        #pragma unroll
        for (int fn=0; fn<4; fn++)
          acc[fm][fn] = __builtin_amdgcn_mfma_f32_16x16x32_f16(af[fm], bfr[fn], acc[fm][fn], 0, 0, 0);
    }
  }

  float* Cb = C;
  if (KS > 1) Cb += (size_t)blockIdx.z * ((size_t)Mtok * Nd);
  #pragma unroll
  for (int fm=0; fm<4; fm++){
    int mbase = m0 + wm*64 + fm*16 + ((lane>>4)<<2);
    #pragma unroll
    for (int fn=0; fn<4; fn++){
      int n = n0 + wn*64 + fn*16 + (lane & 15);
      if (n < Nd){
        #pragma unroll
        for (int r=0;r<4;r++){
          size_t idx = (size_t)(mbase + r)*Nd + n;
          float v = acc[fm][fn][r];
          if (KS > 1) Cb[idx] = v;
          else Cb[idx] = accum ? Cb[idx] + v : v;
        }
      }
    }
  }
}

// C = (accum ? C : 0) + sum_s part[s]   (f32 fallback tier)
__global__ void k_ksum(const float* __restrict__ part, float* __restrict__ C,
                       int Nd, int KS, int accum){
  size_t e = (size_t)blockIdx.x*256 + threadIdx.x;
  size_t tot = (size_t)Mtok*Nd;
  if (e >= tot) return;
  float v = 0.f;
  for (int s=0;s<KS;s++) v += part[(size_t)s*tot + e];
  C[e] = accum ? C[e] + v : v;
}

// Weff = W + 2 * Bl @ Al   (f32 out; fallback tier)
__global__ void k_lora_merge(const float* __restrict__ W, const float* __restrict__ Bl,
    const float* __restrict__ Al, float* __restrict__ out, int Nd, int Kd){
  size_t e = (size_t)blockIdx.x*256 + threadIdx.x;
  if (e >= (size_t)Nd*Kd) return;
  int n = (int)(e / Kd), k = (int)(e % Kd);
  float s = W[e];
  #pragma unroll
  for (int r=0;r<8;r++) s += 2.0f * Bl[n*8+r] * Al[(size_t)r*Kd + k];
  out[e] = s;
}

// Weff = W + 2 * Bl @ Al  -> fp16 out, vectorized x4 along K
__global__ void k_lora_merge_h(const float* __restrict__ W, const float* __restrict__ Bl,
    const float* __restrict__ Al, unsigned short* __restrict__ out, int Nd, int Kd){
  int e4 = blockIdx.x*256 + threadIdx.x;
  int tot4 = Nd*(Kd/4);
  if (e4 >= tot4) return;
  int k4n = Kd/4;
  int n = e4 / k4n, k4 = e4 - n*k4n;
  float4 wv = *(const float4*)(W + (size_t)n*Kd + k4*4);
  float s0=wv.x, s1=wv.y, s2=wv.z, s3=wv.w;
  #pragma unroll
  for (int r=0;r<8;r++){
    float b = 2.0f * Bl[n*8+r];
    float4 a = *(const float4*)(Al + (size_t)r*Kd + k4*4);
    s0 += b*a.x; s1 += b*a.y; s2 += b*a.z; s3 += b*a.w;
  }
  ushort4 o; o.x=f2h(s0); o.y=f2h(s1); o.z=f2h(s2); o.w=f2h(s3);
  ((ushort4*)out)[e4] = o;
}

// fallback rank-8 kernels (f32 tier only)
__global__ __launch_bounds__(256) void k_rank8a(const float* __restrict__ A,
    const float* __restrict__ W8, float* __restrict__ outp, int Kd){
  extern __shared__ float Ws[];
  int tid = threadIdx.x;
  for (int e = tid; e < 8*Kd; e += 256) Ws[e] = W8[e];
  __syncthreads();
  int r = blockIdx.x*64 + (tid >> 2);
  int q = tid & 3;
  const float* Ar = A + (size_t)r*Kd;
  float a0=0.f, a1=0.f;
  for (int k=0;k<Kd;k+=4){
    float4 av = *(const float4*)(Ar + k);
    float4 w0 = *(const float4*)&Ws[q*Kd + k];
    float4 w1 = *(const float4*)&Ws[(q+4)*Kd + k];
    a0 += av.x*w0.x + av.y*w0.y + av.z*w0.z + av.w*w0.w;
    a1 += av.x*w1.x + av.y*w1.y + av.z*w1.z + av.w*w1.w;
  }
  outp[r*8+q] = a0; outp[r*8+q+4] = a1;
}
__global__ void k_rank8b(const float* __restrict__ Tm, const float* __restrict__ W,
    float* __restrict__ C, int Nd){
  size_t gid = (size_t)blockIdx.x*256 + threadIdx.x;
  if (gid >= (size_t)Mtok*Nd) return;
  int m = (int)(gid / Nd), n = (int)(gid % Nd);
  const float* tr = Tm + m*8;
  const float* wr = W + (size_t)n*8;
  float s = 0.f;
  #pragma unroll
  for (int r=0;r<8;r++) s += tr[r]*wr[r];
  C[gid] += 2.0f*s;
}

// ---------------- conv + dt ----------------
__global__ __launch_bounds__(256) void k_conv(const float* __restrict__ zx,
    const float* __restrict__ cw, const float* __restrict__ cb,
    const float* __restrict__ dtb, float* __restrict__ xh, float* __restrict__ Bm,
    float* __restrict__ Cm, float* __restrict__ dtsp){
  int m = blockIdx.x; int b = m >> 9; int t = m & 511;
  int c = blockIdx.y*256 + threadIdx.x;
  if (c < CONVDc){
    float accv = cb[c];
    #pragma unroll
    for (int k=0;k<KC;k++){
      int tt = t + k - (KC-1);
      if (tt >= 0) accv += cw[c*KC + k] * zx[(size_t)(b*Tseq + tt)*DPROJc + DINc + c];
    }
    float v = siluf(accv);
    if (c < DINc)            xh[(size_t)m*DINc + c] = v;
    else if (c < DINc + NS)  Bm[m*NS + (c - DINc)] = v;
    else                     Cm[m*NS + (c - DINc - NS)] = v;
  } else if (c < CONVDc + Hn){
    int h = c - CONVDc;
    float xv = zx[(size_t)m*DPROJc + DINc + CONVDc + h] + dtb[h];
    dtsp[m*Hn + h] = softplusf(xv);
  }
}

// ---------------- SSM scan (SSD chunked, Q=64, NCH=8) ----------------
// k_s1: fused local cumlog (64-lane shuffle scan) + chunk-state outer product.
// Writes S[bh][c][n][p] and per-chunk decay totals ctot[bh][c].
__global__ __launch_bounds__(256) void k_s1(const float* __restrict__ xh,
    const float* __restrict__ Bm, const float* __restrict__ dtsp,
    const float* __restrict__ alog, float* __restrict__ S, float* __restrict__ ctot){
  int bh = blockIdx.x; int b = bh / Hn, h = bh % Hn; int c = blockIdx.y;
  __shared__ float Xc[64][64];
  __shared__ float Bc[64][64];
  __shared__ float wv[64];
  int tid = threadIdx.x;
  int base_m = b*Tseq + c*64;
  for (int e = tid; e < 4096; e += 256){
    int t = e >> 6, p = e & 63;
    Xc[t][p] = xh[(size_t)(base_m + t)*DINc + h*64 + p];
    Bc[t][p] = Bm[(base_m + t)*NS + p];
  }
  if (tid < 64){
    float Av = -expf(alog[h]);
    float dt = dtsp[(base_m + tid)*Hn + h];
    float s = dt * Av;
    #pragma unroll
    for (int o=1;o<64;o<<=1){ float v = __shfl_up(s, o); if (tid >= o) s += v; }
    if (tid == 63) ctot[bh*NCH + c] = s;
    float ce = __shfl(s, 63);
    wv[tid] = expf(ce - s) * dt;
  }
  __syncthreads();
  int tx = tid & 15, ty = tid >> 4;
  int nn0 = 4*tx, p0 = 4*ty;
  float acc[4][4] = {};
  #pragma unroll 4
  for (int t=0;t<64;t++){
    float4 xv = *(const float4*)&Xc[t][p0];
    float4 bv = *(const float4*)&Bc[t][nn0];
    float wt = wv[t];
    float wx[4] = {wt*xv.x, wt*xv.y, wt*xv.z, wt*xv.w};
    float bb[4] = {bv.x, bv.y, bv.z, bv.w};
    #pragma unroll
    for (int i=0;i<4;i++)
      #pragma unroll
      for (int j=0;j<4;j++) acc[i][j] += wx[i]*bb[j];
  }
  float* Sb = S + ((size_t)(bh*NCH + c))*4096;
  #pragma unroll
  for (int j=0;j<4;j++){
    float4 o = make_float4(acc[0][j], acc[1][j], acc[2][j], acc[3][j]);
    *(float4*)&Sb[(nn0+j)*64 + p0] = o;
  }
}

// sequential over chunks: hst[bh][c] = state at chunk start (uses ctot)
__global__ void k_s2(const float* __restrict__ S, const float* __restrict__ ctot,
                     float* __restrict__ hst){
  int gid = blockIdx.x*256 + threadIdx.x;
  int bh = gid >> 12; int e = gid & 4095;
  float hv = 0.f;
  #pragma unroll
  for (int c=0;c<NCH;c++){
    size_t idx = ((size_t)(bh*NCH + c))*4096 + e;
    hst[idx] = hv;
    float Ac = expf(ctot[bh*NCH + c]);
    hv = Ac*hv + S[idx];
  }
}

// k_s3: fused local cumlog + within-chunk attention-form output + state term + D skip
__global__ __launch_bounds__(256) void k_s3(const float* __restrict__ xh,
    const float* __restrict__ Bm, const float* __restrict__ Cm,
    const float* __restrict__ dtsp, const float* __restrict__ alog,
    const float* __restrict__ hst, const float* __restrict__ Dsk,
    float* __restrict__ y){
  int bh = blockIdx.x; int b = bh / Hn, h = bh % Hn; int c = blockIdx.y;
  __shared__ float CcT[64][68];
  __shared__ float BcT[64][68];
  __shared__ float Xc[64][64];
  __shared__ float cumS[64];
  __shared__ float dtS[64];
  int tid = threadIdx.x;
  int base_m = b*Tseq + c*64;
  for (int e = tid; e < 4096; e += 256){
    int t = e >> 6, n = e & 63;
    CcT[n][t] = Cm[(base_m + t)*NS + n];
    BcT[n][t] = Bm[(base_m + t)*NS + n];
    Xc[t][n]  = xh[(size_t)(base_m + t)*DINc + h*64 + n];
  }
  if (tid < 64){
    float Av = -expf(alog[h]);
    float dt = dtsp[(base_m + tid)*Hn + h];
    float s = dt * Av;
    #pragma unroll
    for (int o=1;o<64;o<<=1){ float v = __shfl_up(s, o); if (tid >= o) s += v; }
    cumS[tid] = s;
    dtS[tid]  = dt;
  }
  __syncthreads();
  int tx = tid & 15, ty = tid >> 4;
  int t0 = 4*tx, s0 = 4*ty;
  float G[4][4] = {};
  #pragma unroll 4
  for (int n=0;n<64;n++){
    float4 cv = *(const float4*)&CcT[n][t0];
    float4 bv = *(const float4*)&BcT[n][s0];
    float ca[4]={cv.x,cv.y,cv.z,cv.w}, ba[4]={bv.x,bv.y,bv.z,bv.w};
    #pragma unroll
    for (int i=0;i<4;i++)
      #pragma unroll
      for (int j=0;j<4;j++) G[i][j] += ca[i]*ba[j];
  }
  __syncthreads();
  #pragma unroll
  for (int j=0;j<4;j++){
    int s = s0 + j;
    float4 o;
    float* op = (float*)&o;
    #pragma unroll
    for (int i=0;i<4;i++){
      int t = t0 + i;
      op[i] = (s <= t) ? expf(cumS[t] - cumS[s]) * dtS[s] * G[i][j] : 0.f;
    }
    *(float4*)&BcT[s][t0] = o;
  }
  __syncthreads();
  int p0 = s0;
  float accL[4][4] = {};
  #pragma unroll 4
  for (int s=0;s<64;s++){
    float4 mv = *(const float4*)&BcT[s][t0];
    float4 xv = *(const float4*)&Xc[s][p0];
    float ma[4]={mv.x,mv.y,mv.z,mv.w}, xa[4]={xv.x,xv.y,xv.z,xv.w};
    #pragma unroll
    for (int i=0;i<4;i++)
      #pragma unroll
      for (int j=0;j<4;j++) accL[i][j] += ma[i]*xa[j];
  }
  __syncthreads();
  {
    const float* hb = hst + ((size_t)(bh*NCH + c))*4096;
    for (int e = tid; e < 4096; e += 256) ((float*)Xc)[e] = hb[e];
  }
  __syncthreads();
  float accS[4][4] = {};
  #pragma unroll 4
  for (int n=0;n<64;n++){
    float4 cv = *(const float4*)&CcT[n][t0];
    float4 hv = *(const float4*)&((float*)Xc)[n*64 + p0];
    float ca[4]={cv.x,cv.y,cv.z,cv.w}, ha[4]={hv.x,hv.y,hv.z,hv.w};
    #pragma unroll
    for (int i=0;i<4;i++)
      #pragma unroll
      for (int j=0;j<4;j++) accS[i][j] += ca[i]*ha[j];
  }
  float Dh = Dsk[h];
  #pragma unroll
  for (int i=0;i<4;i++){
    int t = t0 + i;
    int m = base_m + t;
    float Pt = expf(cumS[t]);
    float4 xg = *(const float4*)&xh[(size_t)m*DINc + h*64 + p0];
    float xa[4] = {xg.x,xg.y,xg.z,xg.w};
    float4 o;
    float* op = (float*)&o;
    #pragma unroll
    for (int j=0;j<4;j++) op[j] = accL[i][j] + Pt*accS[i][j] + Dh*xa[j];
    *(float4*)&y[(size_t)m*DINc + h*64 + p0] = o;
  }
}

// y = rms(y * silu(z)) * gw ; writes fp16 yb if given, else f32 y in-place
__global__ __launch_bounds__(256) void k_gate(const float* __restrict__ zx,
    float* __restrict__ y, unsigned short* __restrict__ yb,
    const float* __restrict__ gw){
  int m = blockIdx.x, tid = threadIdx.x;
  __shared__ float sh[4];
  const float* zr = zx + (size_t)m*DPROJc;
  float* yr = y + (size_t)m*DINc;
  float g[6]; float ss = 0.f;
  #pragma unroll
  for (int k=0;k<6;k++){
    int e = tid + k*256;
    float z = zr[e];
    float v = yr[e] * siluf(z);
    g[k] = v; ss += v*v;
  }
  ss = blk_reduce256(ss, sh);
  float rs = 1.0f / sqrtf(ss/(float)DINc + EPSc);
  #pragma unroll
  for (int k=0;k<6;k++){
    int e = tid + k*256;
    float v = g[k]*rs*gw[e];
    if (yb) yb[(size_t)m*DINc + e] = f2h(v);
    else    yr[e] = v;
  }
}

// ---------------- host orchestration ----------------
struct WSP {
  float *x,*res,*xp,*u,*zx,*xh,*Bm,*Cm,*dtsp,*ctot,*Sc,*hst,*y,*tmp8,*part,*iwm,*owm;
  unsigned short *ub,*yb,*wib,*wob,*whb;   // fp16 tier
};

// ---- fp16-tier mixer: out_proj always writes 4 split-K partials to w.part ----
static void run_mixer_h(hipStream_t st, const WSP& w, const unsigned short* ub_in,
    const unsigned short* iw, const float* cw, const float* cb, const float* dtb,
    const float* al, const float* dk, const float* gw, const unsigned short* ow){
  dim3 gIn((DPROJc + 127)/128, Mtok/128, 1);
  k_gemm_h<<<gIn, 256, 0, st>>>(ub_in, iw, w.zx, DPROJc, Dm, 0);
  k_conv<<<dim3(Mtok, 7), 256, 0, st>>>(w.zx, cw, cb, dtb, w.xh, w.Bm, w.Cm, w.dtsp);
  k_s1<<<dim3(Bsz*Hn, NCH), 256, 0, st>>>(w.xh, w.Bm, w.dtsp, al, w.Sc, w.ctot);
  k_s2<<<(Bsz*Hn*4096)/256, 256, 0, st>>>(w.Sc, w.ctot, w.hst);
  k_s3<<<dim3(Bsz*Hn, NCH), 256, 0, st>>>(w.xh, w.Bm, w.Cm, w.dtsp, al, w.hst, dk, w.y);
  k_gate<<<Mtok, 256, 0, st>>>(w.zx, w.y, w.yb, gw);
  dim3 gOut(Dm/128, Mtok/128, 4);      // split-K=4 partials
  k_gemm_h<<<gOut, 256, 0, st>>>(w.yb, ow, w.part, Dm, DINc, 0);
}

// ---- f32 fallback mixer ----
static void run_mixer(hipStream_t st, const WSP& w, const float* u, float* xout,
    int accumOut,
    const float* iw, const float* cw, const float* cb, const float* dtb,
    const float* al, const float* dk, const float* gw, const float* ow,
    const float* iaw, const float* ibw, const float* oaw, const float* obw){
  dim3 gIn((DPROJc + 63)/64, Mtok/128);
  k_gemm<<<gIn, 256, 0, st>>>(u, iw, w.zx, DPROJc, Dm, 1.0f, 0);
  if (iaw){
    k_rank8a<<<Mtok/64, 256, 8*Dm*4, st>>>(u, iaw, w.tmp8, Dm);
    k_rank8b<<<((size_t)Mtok*DPROJc + 255)/256, 256, 0, st>>>(w.tmp8, ibw, w.zx, DPROJc);
  }
  k_conv<<<dim3(Mtok, 7), 256, 0, st>>>(w.zx, cw, cb, dtb, w.xh, w.Bm, w.Cm, w.dtsp);
  k_s1<<<dim3(Bsz*Hn, NCH), 256, 0, st>>>(w.xh, w.Bm, w.dtsp, al, w.Sc, w.ctot);
  k_s2<<<(Bsz*Hn*4096)/256, 256, 0, st>>>(w.Sc, w.ctot, w.hst);
  k_s3<<<dim3(Bsz*Hn, NCH), 256, 0, st>>>(w.xh, w.Bm, w.Cm, w.dtsp, al, w.hst, dk, w.y);
  k_gate<<<Mtok, 256, 0, st>>>(w.zx, w.y, nullptr, gw);
  dim3 gOut(Dm/64, Mtok/128, 8);
  k_gemm<<<gOut, 256, 0, st>>>(w.y, ow, w.part, Dm, DINc, 1.0f, 0);
  k_ksum<<<((size_t)Mtok*Dm + 255)/256, 256, 0, st>>>(w.part, xout, Dm, 8, accumOut);
  if (oaw){
    k_rank8a<<<Mtok/64, 256, 8*DINc*4, st>>>(w.y, oaw, w.tmp8, DINc);
    k_rank8b<<<((size_t)Mtok*Dm + 255)/256, 256, 0, st>>>(w.tmp8, obw, xout, Dm);
  }
}

extern "C" void kernel_launch(void* const* d_in, const int* in_sizes, int n_in,
                              void* d_out, int out_size, void* d_ws, size_t ws_size,
                              hipStream_t stream){
  const int*   ids        = (const int*)  d_in[0];
  // d_in[1] = n_loops (device scalar) -- statically 3; graph must be fixed anyway.
  const float* emb        = (const float*)d_in[2];
  const float* norm_w     = (const float*)d_in[3];
  const float* in_w       = (const float*)d_in[4];
  const float* conv_w     = (const float*)d_in[5];
  const float* conv_b     = (const float*)d_in[6];
  const float* dt_bias    = (const float*)d_in[7];
  const float* A_log      = (const float*)d_in[8];
  const float* D_skip     = (const float*)d_in[9];
  const float* gnorm_w    = (const float*)d_in[10];
  const float* out_w      = (const float*)d_in[11];
  const float* lora_in_A  = (const float*)d_in[12];
  const float* lora_in_B  = (const float*)d_in[13];
  const float* lora_out_A = (const float*)d_in[14];
  const float* lora_out_B = (const float*)d_in[15];
  const float* core_in_w  = (const float*)d_in[16];
  const float* core_conv_w= (const float*)d_in[17];
  const float* core_conv_b= (const float*)d_in[18];
  const float* core_dtb   = (const float*)d_in[19];
  const float* core_A_log = (const float*)d_in[20];
  const float* core_D     = (const float*)d_in[21];
  const float* core_gw    = (const float*)d_in[22];
  const float* core_out_w = (const float*)d_in[23];
  const float* loop_norm_w= (const float*)d_in[24];
  const float* life_gate  = (const float*)d_in[25];
  const float* norm_f_w   = (const float*)d_in[26];
  const float* lm_head_w  = (const float*)d_in[27];
  (void)in_sizes; (void)n_in; (void)out_size;

  char* pb = (char*)d_ws;
  auto balloc = [&](size_t bytes){
    char* q = pb; pb += (bytes + 255) & ~(size_t)255; return q;
  };
  WSP w;
  w.x    = (float*)balloc((size_t)Mtok*Dm*4);
  w.res  = (float*)balloc((size_t)Mtok*Dm*4);
  w.xp   = (float*)balloc((size_t)Mtok*Dm*4);
  w.u    = (float*)balloc((size_t)Mtok*Dm*4);
  w.zx   = (float*)balloc((size_t)Mtok*DPROJc*4);
  w.xh   = (float*)balloc((size_t)Mtok*DINc*4);
  w.Bm   = (float*)balloc((size_t)Mtok*NS*4);
  w.Cm   = (float*)balloc((size_t)Mtok*NS*4);
  w.dtsp = (float*)balloc((size_t)Mtok*Hn*4);
  w.ctot = (float*)balloc((size_t)Bsz*Hn*NCH*4);
  w.Sc   = (float*)balloc((size_t)Bsz*Hn*NCH*4096*4);
  w.hst  = (float*)balloc((size_t)Bsz*Hn*NCH*4096*4);
  w.y    = (float*)balloc((size_t)Mtok*DINc*4);
  w.tmp8 = (float*)balloc((size_t)Mtok*8*4);
  w.part = (float*)balloc((size_t)8*Mtok*Dm*4);

  const size_t IWN = (size_t)DPROJc*Dm;      // 2,476,032
  const size_t OWN = (size_t)Dm*DINc;        // 1,179,648
  const size_t HWN = (size_t)Vv*Dm;          // 38,621,184
  size_t h_bytes = ((size_t)Mtok*Dm + (size_t)Mtok*DINc + 13*IWN + 13*OWN + HWN) * 2
                    + 8*256;
  size_t used = (size_t)(pb - (char*)d_ws);
  bool hTier = (used + h_bytes) <= ws_size;

  if (hTier){
    w.ub  = (unsigned short*)balloc((size_t)Mtok*Dm*2);
    w.yb  = (unsigned short*)balloc((size_t)Mtok*DINc*2);
    w.wib = (unsigned short*)balloc(13*IWN*2);
    w.wob = (unsigned short*)balloc(13*OWN*2);
    w.whb = (unsigned short*)balloc(HWN*2);
    // ---- one-time (per launch) weight conversion / LoRA merge ----
    k_f2h<<<(6*IWN/4 + 255)/256, 256, 0, stream>>>(in_w,  w.wib, (int)(6*IWN/4));
    k_f2h<<<(6*OWN/4 + 255)/256, 256, 0, stream>>>(out_w, w.wob, (int)(6*OWN/4));
    for (int l=0;l<LLO;l++){
      k_lora_merge_h<<<(IWN/4 + 255)/256, 256, 0, stream>>>(
          in_w + (size_t)(SPL+l)*IWN, lora_in_B + (size_t)l*DPROJc*8,
          lora_in_A + (size_t)l*8*Dm, w.wib + (SPL+l)*IWN, DPROJc, Dm);
      k_lora_merge_h<<<(OWN/4 + 255)/256, 256, 0, stream>>>(
          out_w + (size_t)(SPL+l)*OWN, lora_out_B + (size_t)l*Dm*8,
          lora_out_A + (size_t)l*8*DINc, w.wob + (SPL+l)*OWN, Dm, DINc);
    }
    k_f2h<<<(IWN/4 + 255)/256, 256, 0, stream>>>(core_in_w,  w.wib + 12*IWN, (int)(IWN/4));
    k_f2h<<<(OWN/4 + 255)/256, 256, 0, stream>>>(core_out_w, w.wob + 12*OWN, (int)(OWN/4));
    k_f2h<<<(HWN/4 + 255)/256, 256, 0, stream>>>(lm_head_w, w.whb, (int)(HWN/4));
    w.iwm = nullptr; w.owm = nullptr;
  } else {
    w.ub = nullptr; w.yb = nullptr; w.wib = nullptr; w.wob = nullptr; w.whb = nullptr;
    size_t merge_bytes = (size_t)LLO * (IWN + OWN) * 4;
    bool useMerge = (used + merge_bytes) <= ws_size;
    if (useMerge){
      w.iwm = (float*)balloc((size_t)LLO*IWN*4);
      w.owm = (float*)balloc((size_t)LLO*OWN*4);
      for (int l=0;l<LLO;l++){
        k_lora_merge<<<(IWN + 255)/256, 256, 0, stream>>>(
            in_w + (size_t)(SPL+l)*IWN, lora_in_B + (size_t)l*DPROJc*8,
            lora_in_A + (size_t)l*8*Dm, w.iwm + (size_t)l*IWN, DPROJc, Dm);
        k_lora_merge<<<(OWN + 255)/256, 256, 0, stream>>>(
            out_w + (size_t)(SPL+l)*OWN, lora_out_B + (size_t)l*Dm*8,
            lora_out_A + (size_t)l*8*DINc, w.owm + (size_t)l*OWN, Dm, DINc);
      }
    } else { w.iwm = nullptr; w.owm = nullptr; }
  }

  k_embed<<<Mtok, 192, 0, stream>>>(ids, emb, w.x);
  hipMemsetAsync(w.res, 0, (size_t)Mtok*Dm*sizeof(float), stream);

  const size_t totMD = (size_t)Mtok*Dm;

  if (hTier){
    auto mixer_l = [&](int l){
      run_mixer_h(stream, w, w.ub,
          w.wib + (size_t)l*IWN, conv_w + (size_t)l*CONVDc*KC, conv_b + (size_t)l*CONVDc,
          dt_bias + (size_t)l*Hn, A_log + (size_t)l*Hn, D_skip + (size_t)l*Hn,
          gnorm_w + (size_t)l*DINc, w.wob + (size_t)l*OWN);
    };
    // ---- prompt phase ----
    k_addrms<<<Mtok, 256, 0, stream>>>(w.x, w.res, w.u, w.ub, norm_w);
    mixer_l(0);
    for (int l=1; l<NL; l++){
      k_addrms_p<<<Mtok, 256, 0, stream>>>(w.part, w.res, w.u, w.ub, norm_w + (size_t)l*Dm);
      mixer_l(l);
    }
    k_sum_xp<<<(totMD + 255)/256, 256, 0, stream>>>(w.part, w.x, w.xp);
    // ---- loop phase ----
    for (int i=0;i<NLOOPS;i++){
      k_liferope<<<Mtok, 128, 0, stream>>>(w.x, w.xp, life_gate, (float)i);
      k_addrms<<<Mtok, 256, 0, stream>>>(w.x, w.res, w.u, w.ub, norm_w + (size_t)SPL*Dm);
      mixer_l(SPL);
      for (int l=SPL+1; l<NL; l++){
        k_addrms_p<<<Mtok, 256, 0, stream>>>(w.part, w.res, w.u, w.ub, norm_w + (size_t)l*Dm);
        mixer_l(l);
      }
      k_f2h_sum<<<(totMD + 255)/256, 256, 0, stream>>>(w.part, w.x, w.ub);
      run_mixer_h(stream, w, w.ub,
          w.wib + 12*IWN, core_conv_w, core_conv_b, core_dtb, core_A_log, core_D,
          core_gw, w.wob + 12*OWN);
      k_rms_p<<<Mtok, 256, 0, stream>>>(w.part, w.x, loop_norm_w);
    }
    // ---- head ----
    k_addrms<<<Mtok, 256, 0, stream>>>(w.x, w.res, w.u, w.ub, norm_f_w);
    dim3 gHead((Vv + 127)/128, Mtok/128, 1);
    k_gemm_h<<<gHead, 256, 0, stream>>>(w.ub, w.whb, (float*)d_out, Vv, Dm, 0);
    return;
  }

  // ---------------- f32 fallback tier (round-1 structure) ----------------
  auto layer = [&](int l, bool lora){
    k_addrms<<<Mtok, 256, 0, stream>>>(w.x, w.res, w.u, nullptr, norm_w + (size_t)l*Dm);
    const float *iw, *ow, *iaw=nullptr, *ibw=nullptr, *oaw=nullptr, *obw=nullptr;
    if (lora && w.iwm){
      int ll = l - SPL;
      iw = w.iwm + (size_t)ll*IWN;
      ow = w.owm + (size_t)ll*OWN;
    } else {
      iw = in_w + (size_t)l*IWN;
      ow = out_w + (size_t)l*OWN;
      if (lora){
        int ll = l - SPL;
        iaw = lora_in_A + (size_t)ll*8*Dm;    ibw = lora_in_B + (size_t)ll*DPROJc*8;
        oaw = lora_out_A + (size_t)ll*8*DINc; obw = lora_out_B + (size_t)ll*Dm*8;
      }
    }
    run_mixer(stream, w, w.u, w.x, 0,
        iw, conv_w + (size_t)l*CONVDc*KC, conv_b + (size_t)l*CONVDc,
        dt_bias + (size_t)l*Hn, A_log + (size_t)l*Hn, D_skip + (size_t)l*Hn,
        gnorm_w + (size_t)l*DINc, ow, iaw, ibw, oaw, obw);
  };

  for (int l=0; l<SPL; l++) layer(l, false);
  for (int l=SPL; l<NL; l++) layer(l, true);
  hipMemcpyAsync(w.xp, w.x, totMD*sizeof(float), hipMemcpyDeviceToDevice, stream);
  for (int i=0;i<NLOOPS;i++){
    k_liferope<<<Mtok, 128, 0, stream>>>(w.x, w.xp, life_gate, (float)i);
    for (int l=SPL; l<NL; l++) layer(l, true);
    run_mixer(stream, w, w.x, w.x, 1,
        core_in_w, core_conv_w, core_conv_b, core_dtb, core_A_log, core_D,
        core_gw, core_out_w, nullptr, nullptr, nullptr, nullptr);
    k_rms<<<Mtok, 256, 0, stream>>>(w.x, w.x, loop_norm_w);
  }
  k_addrms<<<Mtok, 256, 0, stream>>>(w.x, w.res, w.u, nullptr, norm_f_w);
  dim3 gHead((Vv + 63)/64, Mtok/128);
  k_gemm<<<gHead, 256, 0, stream>>>(w.u, lm_head_w, (float*)d_out, Vv, Dm, 1.0f, 0);
}

// Round 5
// 4133.769 us; speedup vs baseline: 1.8434x; 1.0840x over previous
//
#include <hip/hip_runtime.h>
#include <math.h>

// ---------------- constants (match reference) ----------------
constexpr int Bsz   = 2;
constexpr int Tseq  = 512;
constexpr int Mtok  = Bsz * Tseq;      // 1024 tokens
constexpr int Dm    = 768;
constexpr int DINc  = 1536;
constexpr int Hn    = 24;
constexpr int NS    = 64;
constexpr int KC    = 4;
constexpr int DPROJc = 2*DINc + 2*NS + Hn;  // 3224
constexpr int CONVDc = DINc + 2*NS;         // 1664
constexpr int NL    = 12;
constexpr int SPL   = 6;
constexpr int LLO   = 6;
constexpr int NCH   = 8;                   // chunks of 64 along T
constexpr int Vv    = 50288;
constexpr float EPSc = 1e-5f;
constexpr int NLOOPS = 3;                  // n_loops (static in setup_inputs)

#define DEVI __device__ __forceinline__

typedef _Float16 f16x8 __attribute__((ext_vector_type(8)));
typedef float    f32x4 __attribute__((ext_vector_type(4)));

DEVI float siluf(float x){ return x / (1.0f + expf(-x)); }
DEVI float softplusf(float x){ return (x > 20.0f) ? x : log1pf(expf(x)); }
DEVI unsigned short f2h(float f){
  union { _Float16 h; unsigned short u; } c;
  c.h = (_Float16)f;                      // RTNE
  return c.u;
}
DEVI float h2f(unsigned short u){
  union { unsigned short u; _Float16 h; } c;
  c.u = u; return (float)c.h;
}

DEVI float blk_reduce256(float v, float* sh){
  #pragma unroll
  for (int o = 32; o; o >>= 1) v += __shfl_down(v, o);
  int lane = threadIdx.x & 63, w = threadIdx.x >> 6;
  if (lane == 0) sh[w] = v;
  __syncthreads();
  return sh[0] + sh[1] + sh[2] + sh[3];
}

// ---------------- small kernels ----------------
__global__ void k_embed(const int* __restrict__ ids, const float* __restrict__ emb,
                        float* __restrict__ x){
  int m = blockIdx.x;
  int id = ids[m];
  const float4* src = (const float4*)(emb + (size_t)id * Dm);
  float4* dst = (float4*)(x + (size_t)m * Dm);
  int i = threadIdx.x;            // blockDim = 192 = 768/4
  dst[i] = src[i];
}

// f32 -> fp16 convert, 4 elems/thread
__global__ void k_f2h(const float* __restrict__ in, unsigned short* __restrict__ out, int n4){
  int e = blockIdx.x*256 + threadIdx.x;
  if (e >= n4) return;
  float4 v = ((const float4*)in)[e];
  ushort4 o; o.x=f2h(v.x); o.y=f2h(v.y); o.z=f2h(v.z); o.w=f2h(v.w);
  ((ushort4*)out)[e] = o;
}

// res = x + res ; ub = fp16(rms(res) * w)
__global__ __launch_bounds__(256) void k_addrms(const float* __restrict__ xin,
    float* __restrict__ res, unsigned short* __restrict__ ub,
    const float* __restrict__ w){
  int m = blockIdx.x, tid = threadIdx.x;
  __shared__ float sh[4];
  const float* xr = xin + (size_t)m*Dm;
  float* rr = res + (size_t)m*Dm;
  float r[3]; float ss = 0.f;
  #pragma unroll
  for (int k=0;k<3;k++){ int e = tid + k*256; float v = xr[e] + rr[e]; r[k]=v; ss += v*v; }
  ss = blk_reduce256(ss, sh);
  float rs = 1.0f / sqrtf(ss/(float)Dm + EPSc);
  #pragma unroll
  for (int k=0;k<3;k++){
    int e = tid + k*256;
    rr[e] = r[k];
    ub[(size_t)m*Dm+e] = f2h(r[k]*rs*w[e]);
  }
}

// res = (sum of 4 split-K partials) + res ; ub = fp16(rms(res)*w)
__global__ __launch_bounds__(256) void k_addrms_p(const float* __restrict__ part,
    float* __restrict__ res, unsigned short* __restrict__ ub,
    const float* __restrict__ w){
  int m = blockIdx.x, tid = threadIdx.x;
  __shared__ float sh[4];
  const size_t tot = (size_t)Mtok*Dm;
  float* rr = res + (size_t)m*Dm;
  float r[3]; float ss = 0.f;
  #pragma unroll
  for (int k=0;k<3;k++){
    int e = tid + k*256;
    size_t idx = (size_t)m*Dm + e;
    float v = rr[e] + part[idx] + part[tot+idx] + part[2*tot+idx] + part[3*tot+idx];
    r[k]=v; ss += v*v;
  }
  ss = blk_reduce256(ss, sh);
  float rs = 1.0f / sqrtf(ss/(float)Dm + EPSc);
  #pragma unroll
  for (int k=0;k<3;k++){
    int e = tid + k*256;
    rr[e] = r[k];
    ub[(size_t)m*Dm+e] = f2h(r[k]*rs*w[e]);
  }
}

// x = sum parts ; xp = x   (prompt-end snapshot)
__global__ void k_sum_xp(const float* __restrict__ part, float* __restrict__ x,
                         float* __restrict__ xp){
  size_t e = (size_t)blockIdx.x*256 + threadIdx.x;
  const size_t tot = (size_t)Mtok*Dm;
  if (e >= tot) return;
  float v = part[e] + part[tot+e] + part[2*tot+e] + part[3*tot+e];
  x[e] = v; xp[e] = v;
}

// x = sum parts ; ub = fp16(x)   (core-mixer input)
__global__ void k_f2h_sum(const float* __restrict__ part, float* __restrict__ x,
                          unsigned short* __restrict__ ub){
  size_t e = (size_t)blockIdx.x*256 + threadIdx.x;
  const size_t tot = (size_t)Mtok*Dm;
  if (e >= tot) return;
  float v = part[e] + part[tot+e] + part[2*tot+e] + part[3*tot+e];
  x[e] = v; ub[e] = f2h(v);
}

// x = rms(x + sum parts) * w   (loop norm, in-place)
__global__ __launch_bounds__(256) void k_rms_p(const float* __restrict__ part,
    float* __restrict__ x, const float* __restrict__ w){
  int m = blockIdx.x, tid = threadIdx.x;
  __shared__ float sh[4];
  const size_t tot = (size_t)Mtok*Dm;
  float* xr = x + (size_t)m*Dm;
  float r[3]; float ss = 0.f;
  #pragma unroll
  for (int k=0;k<3;k++){
    int e = tid + k*256;
    size_t idx = (size_t)m*Dm + e;
    float v = xr[e] + part[idx] + part[tot+idx] + part[2*tot+idx] + part[3*tot+idx];
    r[k]=v; ss += v*v;
  }
  ss = blk_reduce256(ss, sh);
  float rs = 1.0f / sqrtf(ss/(float)Dm + EPSc);
  #pragma unroll
  for (int k=0;k<3;k++){ int e = tid + k*256; xr[e] = r[k]*rs*w[e]; }
}

// x = rope(x + gate*xp, loop_i)
__global__ __launch_bounds__(128) void k_liferope(float* __restrict__ x,
    const float* __restrict__ xp, const float* __restrict__ gate, float iF){
  int m = blockIdx.x, tid = threadIdx.x;
  float* xr = x + (size_t)m*Dm;
  const float* pr = xp + (size_t)m*Dm;
  #pragma unroll
  for (int k=0;k<3;k++){
    int j = tid + k*128;               // pair index < 384
    int d0 = 2*j, d1 = d0+1;
    float v0 = xr[d0] + gate[d0]*pr[d0];
    float v1 = xr[d1] + gate[d1]*pr[d1];
    float invf = expf(-9.210340371976184f * ((float)(2*j) * (1.0f/768.0f)));
    float f = iF * invf;
    float cv = cosf(f), sv = sinf(f);
    xr[d0] = v0*cv - v1*sv;
    xr[d1] = v1*cv + v0*sv;
  }
}

// ---------------- fp16 MFMA GEMM: C[M,N] = A[M,K] * W[N,K]^T ----------------
// 128x128 tile, 4 waves (2x2), each wave 64x64 via 4x4 mfma_f32_16x16x32_f16.
// BK=64, reg-staged global->LDS with XOR swizzle; bijective XCD-chunk block
// remap (m-fastest inside a chunk) so consecutive logical blocks share the
// weight panel within one XCD's L2.
// outmode: 0 = f32 split-K partial (KS=gridDim.z), 1 = f32 direct, 2 = fp16 direct
__global__ __launch_bounds__(256) void k_gemm_h(
    const unsigned short* __restrict__ A,
    const unsigned short* __restrict__ Bw,
    void* __restrict__ Cv, int Nd, int Kd, int outmode){
  alignas(16) __shared__ unsigned short lA[128*64];
  alignas(16) __shared__ unsigned short lB[128*64];
  const int tid  = threadIdx.x;
  const int lane = tid & 63;
  const int wv   = tid >> 6;
  const int wm   = wv >> 1, wn = wv & 1;
  // bijective XCD-chunk swizzle
  const int gx = gridDim.x, gy = gridDim.y;
  const int nwg = gx*gy;
  const int flat = blockIdx.x + gx*blockIdx.y;
  const int q = nwg >> 3, r = nwg & 7;
  const int xcd = flat & 7, pos = flat >> 3;
  const int lg = (xcd < r ? xcd*(q+1) : r*(q+1) + (xcd - r)*q) + pos;
  const int m_idx = lg % gy, n_idx = lg / gy;
  const int n0 = n_idx * 128;
  const int m0 = m_idx * 128;
  const int KS = gridDim.z;
  const int kchunk = Kd / KS;         // multiple of 64
  const int kbeg = blockIdx.z * kchunk;
  const int nsteps = kchunk / 64;

  f32x4 acc[4][4] = {};
  uint4 ra[4], rb[4];

  auto load_tile = [&](int k0){
    #pragma unroll
    for (int i=0;i<4;i++){
      int seg = tid + i*256;
      int row = seg >> 3;
      int c8  = (seg & 7) ^ (row & 7);
      ra[i] = *(const uint4*)(A + (size_t)(m0 + row)*Kd + k0 + c8*8);
      int rn = n0 + row; rn = (rn < Nd) ? rn : (Nd - 1);
      rb[i] = *(const uint4*)(Bw + (size_t)rn*Kd + k0 + c8*8);
    }
  };

  load_tile(kbeg);
  for (int t=0; t<nsteps; ++t){
    __syncthreads();
    #pragma unroll
    for (int i=0;i<4;i++){
      *(uint4*)((char*)lA + (tid + i*256)*16) = ra[i];
      *(uint4*)((char*)lB + (tid + i*256)*16) = rb[i];
    }
    if (t+1 < nsteps) load_tile(kbeg + (t+1)*64);
    __syncthreads();
    #pragma unroll
    for (int kk=0; kk<2; kk++){
      f16x8 af[4], bfr[4];
      #pragma unroll
      for (int f=0; f<4; f++){
        int rowa = wm*64 + f*16 + (lane & 15);
        int ba = rowa*128 + ((kk*64 + (lane>>4)*16) ^ ((rowa & 7) << 4));
        af[f] = *(const f16x8*)((const char*)lA + ba);
        int rowb = wn*64 + f*16 + (lane & 15);
        int bb = rowb*128 + ((kk*64 + (lane>>4)*16) ^ ((rowb & 7) << 4));
        bfr[f] = *(const f16x8*)((const char*)lB + bb);
      }
      #pragma unroll
      for (int fm=0; fm<4; fm++)
        #pragma unroll
        for (int fn=0; fn<4; fn++)
          acc[fm][fn] = __builtin_amdgcn_mfma_f32_16x16x32_f16(af[fm], bfr[fn], acc[fm][fn], 0, 0, 0);
    }
  }

  #pragma unroll
  for (int fm=0; fm<4; fm++){
    int mbase = m0 + wm*64 + fm*16 + ((lane>>4)<<2);
    #pragma unroll
    for (int fn=0; fn<4; fn++){
      int n = n0 + wn*64 + fn*16 + (lane & 15);
      if (n < Nd){
        #pragma unroll
        for (int rr=0;rr<4;rr++){
          size_t idx = (size_t)(mbase + rr)*Nd + n;
          float v = acc[fm][fn][rr];
          if (outmode == 0){
            float* Cb = (float*)Cv + (size_t)blockIdx.z*((size_t)Mtok*Nd);
            Cb[idx] = v;
          } else if (outmode == 1){
            ((float*)Cv)[idx] = v;
          } else {
            ((unsigned short*)Cv)[idx] = f2h(v);
          }
        }
      }
    }
  }
}

// Weff = W + 2 * Bl @ Al  -> fp16 out, vectorized x4 along K
__global__ void k_lora_merge_h(const float* __restrict__ W, const float* __restrict__ Bl,
    const float* __restrict__ Al, unsigned short* __restrict__ out, int Nd, int Kd){
  int e4 = blockIdx.x*256 + threadIdx.x;
  int tot4 = Nd*(Kd/4);
  if (e4 >= tot4) return;
  int k4n = Kd/4;
  int n = e4 / k4n, k4 = e4 - n*k4n;
  float4 wv = *(const float4*)(W + (size_t)n*Kd + k4*4);
  float s0=wv.x, s1=wv.y, s2=wv.z, s3=wv.w;
  #pragma unroll
  for (int r=0;r<8;r++){
    float b = 2.0f * Bl[n*8+r];
    float4 a = *(const float4*)(Al + (size_t)r*Kd + k4*4);
    s0 += b*a.x; s1 += b*a.y; s2 += b*a.z; s3 += b*a.w;
  }
  ushort4 o; o.x=f2h(s0); o.y=f2h(s1); o.z=f2h(s2); o.w=f2h(s3);
  ((ushort4*)out)[e4] = o;
}

// ---------------- SSD scan, MFMA + fused conv ----------------
// LDS fragment loaders: operand layout row=lane&15(+16*f+32*wz), k=(lane>>4)*8+j
DEVI f16x8 ldfrag(const unsigned short (*T)[72], int row, int k0){
  return *(const f16x8*)&T[row][k0];
}

// k_s1: fused conv(x,B) + dt-scan + chunk-state via MFMA.
// Writes S^T[bh][c][p][n] (f32) and per-chunk decay totals ctot.
__global__ __launch_bounds__(256) void k_s1(const unsigned short* __restrict__ zxh,
    const float* __restrict__ cw, const float* __restrict__ cb,
    const float* __restrict__ dtb, const float* __restrict__ alog,
    float* __restrict__ S, float* __restrict__ ctot){
  int bh = blockIdx.x; int b = bh / Hn, h = bh % Hn; int c = blockIdx.y;
  __shared__ unsigned short XT[64][72];    // XT[p][t] = x[t][p]
  __shared__ unsigned short BwT[64][72];   // BwT[n][t] = w_t * B[t][n]
  __shared__ float wv[64];
  int tid = threadIdx.x;
  int base_m = b*Tseq + c*64;
  // --- dt scan (wave 0) ---
  if (tid < 64){
    float Av = -expf(alog[h]);
    float zdt = h2f(zxh[(size_t)(base_m+tid)*DPROJc + DINc + CONVDc + h]) + dtb[h];
    float dt = softplusf(zdt);
    float s = dt * Av;
    #pragma unroll
    for (int o=1;o<64;o<<=1){ float v = __shfl_up(s, o); if (tid >= o) s += v; }
    if (tid == 63) ctot[bh*NCH + c] = s;
    float ce = __shfl(s, 63);
    wv[tid] = expf(ce - s) * dt;
  }
  __syncthreads();
  int ch = tid & 63;          // channel index (p for X pass, n for B pass)
  int t0 = (tid >> 6) * 16;   // this thread covers t0..t0+15
  int tl = c*64 + t0;         // batch-local row of t0
  // --- X pass: conv channel h*64+ch -> XT[ch][t] ---
  {
    int cc = h*64 + ch;
    float4 w4 = *(const float4*)&cw[cc*KC];
    float bias = cb[cc];
    const unsigned short* zp = zxh + (size_t)base_m*DPROJc + DINc + cc;
    float v0 = (tl >= 3) ? h2f(zp[(long)(t0-3)*DPROJc]) : 0.f;
    float v1 = (tl >= 2) ? h2f(zp[(long)(t0-2)*DPROJc]) : 0.f;
    float v2 = (tl >= 1) ? h2f(zp[(long)(t0-1)*DPROJc]) : 0.f;
    #pragma unroll
    for (int i=0;i<16;i++){
      float v3 = h2f(zp[(long)(t0+i)*DPROJc]);
      float o = bias + w4.x*v0 + w4.y*v1 + w4.z*v2 + w4.w*v3;
      XT[ch][t0+i] = f2h(siluf(o));
      v0=v1; v1=v2; v2=v3;
    }
  }
  // --- B pass: conv channel DINc+ch -> BwT[ch][t] = w_t * B ---
  {
    int cc = DINc + ch;
    float4 w4 = *(const float4*)&cw[cc*KC];
    float bias = cb[cc];
    const unsigned short* zp = zxh + (size_t)base_m*DPROJc + DINc + cc;
    float v0 = (tl >= 3) ? h2f(zp[(long)(t0-3)*DPROJc]) : 0.f;
    float v1 = (tl >= 2) ? h2f(zp[(long)(t0-2)*DPROJc]) : 0.f;
    float v2 = (tl >= 1) ? h2f(zp[(long)(t0-1)*DPROJc]) : 0.f;
    #pragma unroll
    for (int i=0;i<16;i++){
      float v3 = h2f(zp[(long)(t0+i)*DPROJc]);
      float o = bias + w4.x*v0 + w4.y*v1 + w4.z*v2 + w4.w*v3;
      BwT[ch][t0+i] = f2h(siluf(o) * wv[t0+i]);
      v0=v1; v1=v2; v2=v3;
    }
  }
  __syncthreads();
  // --- S^T[p][n] = sum_t XT[p][t] * BwT[n][t] ---
  int lane = tid & 63, wid = tid >> 6, wmp = wid >> 1, wnn = wid & 1;
  f32x4 acc[2][2] = {};
  #pragma unroll
  for (int kk=0; kk<2; kk++){
    int k0 = kk*32 + (lane>>4)*8;
    f16x8 a[2], bf[2];
    #pragma unroll
    for (int f=0; f<2; f++){
      a[f]  = ldfrag(XT,  wmp*32 + f*16 + (lane&15), k0);
      bf[f] = ldfrag(BwT, wnn*32 + f*16 + (lane&15), k0);
    }
    #pragma unroll
    for (int fm=0; fm<2; fm++)
      #pragma unroll
      for (int fn=0; fn<2; fn++)
        acc[fm][fn] = __builtin_amdgcn_mfma_f32_16x16x32_f16(a[fm], bf[fn], acc[fm][fn], 0, 0, 0);
  }
  float* Sb = S + ((size_t)(bh*NCH + c))*4096;
  #pragma unroll
  for (int fm=0; fm<2; fm++)
    #pragma unroll
    for (int fn=0; fn<2; fn++)
      #pragma unroll
      for (int rg=0; rg<4; rg++){
        int p = wmp*32 + fm*16 + ((lane>>4)<<2) + rg;
        int n = wnn*32 + fn*16 + (lane&15);
        Sb[p*64 + n] = acc[fm][fn][rg];
      }
}

// sequential over chunks: hst[bh][c] = state at chunk start (elementwise, layout-agnostic)
__global__ void k_s2(const float* __restrict__ S, const float* __restrict__ ctot,
                     float* __restrict__ hst){
  int gid = blockIdx.x*256 + threadIdx.x;
  int bh = gid >> 12; int e = gid & 4095;
  float hv = 0.f;
  #pragma unroll
  for (int c=0;c<NCH;c++){
    size_t idx = ((size_t)(bh*NCH + c))*4096 + e;
    hst[idx] = hv;
    float Ac = expf(ctot[bh*NCH + c]);
    hv = Ac*hv + S[idx];
  }
}

// k_s3: fused conv(x,B,C) + dt-scan + within-chunk attention-form + state + D skip.
// All four 64^3 matmuls via MFMA. Writes y fp16.
__global__ __launch_bounds__(256) void k_s3(const unsigned short* __restrict__ zxh,
    const float* __restrict__ cw, const float* __restrict__ cb,
    const float* __restrict__ dtb, const float* __restrict__ alog,
    const float* __restrict__ hst, const float* __restrict__ Dsk,
    unsigned short* __restrict__ y){
  int bh = blockIdx.x; int b = bh / Hn, h = bh % Hn; int c = blockIdx.y;
  __shared__ unsigned short Ch[64][72];   // Ch[t][n]
  __shared__ unsigned short Bh[64][72];   // Bh[s][n]
  __shared__ unsigned short XhT[64][72];  // XhT[p][t] = x[t][p]
  __shared__ unsigned short hT[64][72];   // hT[p][n] (= hst stored [p][n])
  __shared__ unsigned short Mh[64][72];   // Mh[t][s]
  __shared__ float cumS[64], dtS[64];
  int tid = threadIdx.x;
  int base_m = b*Tseq + c*64;
  // --- dt scan ---
  if (tid < 64){
    float Av = -expf(alog[h]);
    float zdt = h2f(zxh[(size_t)(base_m+tid)*DPROJc + DINc + CONVDc + h]) + dtb[h];
    float dt = softplusf(zdt);
    float s = dt * Av;
    #pragma unroll
    for (int o=1;o<64;o<<=1){ float v = __shfl_up(s, o); if (tid >= o) s += v; }
    cumS[tid] = s;
    dtS[tid]  = dt;
  }
  int ch = tid & 63;
  int t0 = (tid >> 6) * 16;
  int tl = c*64 + t0;
  // --- X pass -> XhT[ch][t] ---
  {
    int cc = h*64 + ch;
    float4 w4 = *(const float4*)&cw[cc*KC];
    float bias = cb[cc];
    const unsigned short* zp = zxh + (size_t)base_m*DPROJc + DINc + cc;
    float v0 = (tl >= 3) ? h2f(zp[(long)(t0-3)*DPROJc]) : 0.f;
    float v1 = (tl >= 2) ? h2f(zp[(long)(t0-2)*DPROJc]) : 0.f;
    float v2 = (tl >= 1) ? h2f(zp[(long)(t0-1)*DPROJc]) : 0.f;
    #pragma unroll
    for (int i=0;i<16;i++){
      float v3 = h2f(zp[(long)(t0+i)*DPROJc]);
      float o = bias + w4.x*v0 + w4.y*v1 + w4.z*v2 + w4.w*v3;
      XhT[ch][t0+i] = f2h(siluf(o));
      v0=v1; v1=v2; v2=v3;
    }
  }
  // --- B pass -> Bh[t][ch] (natural) ---
  {
    int cc = DINc + ch;
    float4 w4 = *(const float4*)&cw[cc*KC];
    float bias = cb[cc];
    const unsigned short* zp = zxh + (size_t)base_m*DPROJc + DINc + cc;
    float v0 = (tl >= 3) ? h2f(zp[(long)(t0-3)*DPROJc]) : 0.f;
    float v1 = (tl >= 2) ? h2f(zp[(long)(t0-2)*DPROJc]) : 0.f;
    float v2 = (tl >= 1) ? h2f(zp[(long)(t0-1)*DPROJc]) : 0.f;
    #pragma unroll
    for (int i=0;i<16;i++){
      float v3 = h2f(zp[(long)(t0+i)*DPROJc]);
      float o = bias + w4.x*v0 + w4.y*v1 + w4.z*v2 + w4.w*v3;
      Bh[t0+i][ch] = f2h(siluf(o));
      v0=v1; v1=v2; v2=v3;
    }
  }
  // --- C pass -> Ch[t][ch] (natural) ---
  {
    int cc = DINc + NS + ch;
    float4 w4 = *(const float4*)&cw[cc*KC];
    float bias = cb[cc];
    const unsigned short* zp = zxh + (size_t)base_m*DPROJc + DINc + cc;
    float v0 = (tl >= 3) ? h2f(zp[(long)(t0-3)*DPROJc]) : 0.f;
    float v1 = (tl >= 2) ? h2f(zp[(long)(t0-2)*DPROJc]) : 0.f;
    float v2 = (tl >= 1) ? h2f(zp[(long)(t0-1)*DPROJc]) : 0.f;
    #pragma unroll
    for (int i=0;i<16;i++){
      float v3 = h2f(zp[(long)(t0+i)*DPROJc]);
      float o = bias + w4.x*v0 + w4.y*v1 + w4.z*v2 + w4.w*v3;
      Ch[t0+i][ch] = f2h(siluf(o));
      v0=v1; v1=v2; v2=v3;
    }
  }
  // --- hT stage (hst already [p][n]) ---
  {
    const float* hb = hst + ((size_t)(bh*NCH + c))*4096;
    for (int e4 = tid; e4 < 1024; e4 += 256){
      float4 hv = ((const float4*)hb)[e4];
      int p = (e4 << 2) >> 6, n = (e4 << 2) & 63;
      ushort4 o; o.x=f2h(hv.x); o.y=f2h(hv.y); o.z=f2h(hv.z); o.w=f2h(hv.w);
      *(ushort4*)&hT[p][n] = o;
    }
  }
  __syncthreads();
  int lane = tid & 63, wid = tid >> 6, wmt = wid >> 1, wns = wid & 1;
  // --- G[t][s] = sum_n Ch[t][n] Bh[s][n] ---
  f32x4 g[2][2] = {};
  #pragma unroll
  for (int kk=0; kk<2; kk++){
    int k0 = kk*32 + (lane>>4)*8;
    f16x8 a[2], bf[2];
    #pragma unroll
    for (int f=0; f<2; f++){
      a[f]  = ldfrag(Ch, wmt*32 + f*16 + (lane&15), k0);
      bf[f] = ldfrag(Bh, wns*32 + f*16 + (lane&15), k0);
    }
    #pragma unroll
    for (int fm=0; fm<2; fm++)
      #pragma unroll
      for (int fn=0; fn<2; fn++)
        g[fm][fn] = __builtin_amdgcn_mfma_f32_16x16x32_f16(a[fm], bf[fn], g[fm][fn], 0, 0, 0);
  }
  // --- mask + decay -> Mh[t][s] fp16 ---
  #pragma unroll
  for (int fm=0; fm<2; fm++)
    #pragma unroll
    for (int fn=0; fn<2; fn++)
      #pragma unroll
      for (int rg=0; rg<4; rg++){
        int t = wmt*32 + fm*16 + ((lane>>4)<<2) + rg;
        int s = wns*32 + fn*16 + (lane&15);
        float val = (s <= t) ? expf(cumS[t] - cumS[s]) * dtS[s] * g[fm][fn][rg] : 0.f;
        Mh[t][s] = f2h(val);
      }
  __syncthreads();
  // --- accL[t][p] = sum_s Mh[t][s] XhT[p][s]; accS[t][p] = sum_n Ch[t][n] hT[p][n] ---
  f32x4 aL[2][2] = {}, aS[2][2] = {};
  #pragma unroll
  for (int kk=0; kk<2; kk++){
    int k0 = kk*32 + (lane>>4)*8;
    f16x8 m_[2], x_[2], c_[2], h_[2];
    #pragma unroll
    for (int f=0; f<2; f++){
      m_[f] = ldfrag(Mh,  wmt*32 + f*16 + (lane&15), k0);
      x_[f] = ldfrag(XhT, wns*32 + f*16 + (lane&15), k0);
      c_[f] = ldfrag(Ch,  wmt*32 + f*16 + (lane&15), k0);
      h_[f] = ldfrag(hT,  wns*32 + f*16 + (lane&15), k0);
    }
    #pragma unroll
    for (int fm=0; fm<2; fm++)
      #pragma unroll
      for (int fn=0; fn<2; fn++){
        aL[fm][fn] = __builtin_amdgcn_mfma_f32_16x16x32_f16(m_[fm], x_[fn], aL[fm][fn], 0, 0, 0);
        aS[fm][fn] = __builtin_amdgcn_mfma_f32_16x16x32_f16(c_[fm], h_[fn], aS[fm][fn], 0, 0, 0);
      }
  }
  // --- epilogue: y = accL + exp(cum_t)*accS + D*x ---
  float Dh = Dsk[h];
  #pragma unroll
  for (int fm=0; fm<2; fm++)
    #pragma unroll
    for (int fn=0; fn<2; fn++)
      #pragma unroll
      for (int rg=0; rg<4; rg++){
        int t = wmt*32 + fm*16 + ((lane>>4)<<2) + rg;
        int p = wns*32 + fn*16 + (lane&15);
        float Pt = expf(cumS[t]);
        float xv = h2f(XhT[p][t]);
        float o = aL[fm][fn][rg] + Pt*aS[fm][fn][rg] + Dh*xv;
        y[(size_t)(base_m+t)*DINc + h*64 + p] = f2h(o);
      }
}

// yb = fp16(rms(y * silu(z)) * gw) ; y fp16, z from zxh fp16
__global__ __launch_bounds__(256) void k_gate(const unsigned short* __restrict__ zxh,
    const unsigned short* __restrict__ y, unsigned short* __restrict__ yb,
    const float* __restrict__ gw){
  int m = blockIdx.x, tid = threadIdx.x;
  __shared__ float sh[4];
  const unsigned short* zr = zxh + (size_t)m*DPROJc;
  const unsigned short* yr = y + (size_t)m*DINc;
  float g[6]; float ss = 0.f;
  #pragma unroll
  for (int k=0;k<6;k++){
    int e = tid + k*256;
    float z = h2f(zr[e]);
    float v = h2f(yr[e]) * siluf(z);
    g[k] = v; ss += v*v;
  }
  ss = blk_reduce256(ss, sh);
  float rs = 1.0f / sqrtf(ss/(float)DINc + EPSc);
  #pragma unroll
  for (int k=0;k<6;k++){
    int e = tid + k*256;
    yb[(size_t)m*DINc + e] = f2h(g[k]*rs*gw[e]);
  }
}

// ---------------- host orchestration ----------------
struct WSP {
  float *x,*res,*xp,*ctot,*Sc,*hst,*part;
  unsigned short *zxh,*yh,*ub,*yb,*wib,*wob,*whb;
};

static void run_mixer_h(hipStream_t st, const WSP& w, const unsigned short* ub_in,
    const unsigned short* iw, const float* cw, const float* cb, const float* dtb,
    const float* al, const float* dk, const float* gw, const unsigned short* ow){
  dim3 gIn((DPROJc + 127)/128, Mtok/128, 1);
  k_gemm_h<<<gIn, 256, 0, st>>>(ub_in, iw, w.zxh, DPROJc, Dm, 2);
  k_s1<<<dim3(Bsz*Hn, NCH), 256, 0, st>>>(w.zxh, cw, cb, dtb, al, w.Sc, w.ctot);
  k_s2<<<(Bsz*Hn*4096)/256, 256, 0, st>>>(w.Sc, w.ctot, w.hst);
  k_s3<<<dim3(Bsz*Hn, NCH), 256, 0, st>>>(w.zxh, cw, cb, dtb, al, w.hst, dk, w.yh);
  k_gate<<<Mtok, 256, 0, st>>>(w.zxh, w.yh, w.yb, gw);
  dim3 gOut(Dm/128, Mtok/128, 4);      // split-K=4 partials
  k_gemm_h<<<gOut, 256, 0, st>>>(w.yb, ow, w.part, Dm, DINc, 0);
}

extern "C" void kernel_launch(void* const* d_in, const int* in_sizes, int n_in,
                              void* d_out, int out_size, void* d_ws, size_t ws_size,
                              hipStream_t stream){
  const int*   ids        = (const int*)  d_in[0];
  // d_in[1] = n_loops (device scalar) -- statically 3; graph must be fixed anyway.
  const float* emb        = (const float*)d_in[2];
  const float* norm_w     = (const float*)d_in[3];
  const float* in_w       = (const float*)d_in[4];
  const float* conv_w     = (const float*)d_in[5];
  const float* conv_b     = (const float*)d_in[6];
  const float* dt_bias    = (const float*)d_in[7];
  const float* A_log      = (const float*)d_in[8];
  const float* D_skip     = (const float*)d_in[9];
  const float* gnorm_w    = (const float*)d_in[10];
  const float* out_w      = (const float*)d_in[11];
  const float* lora_in_A  = (const float*)d_in[12];
  const float* lora_in_B  = (const float*)d_in[13];
  const float* lora_out_A = (const float*)d_in[14];
  const float* lora_out_B = (const float*)d_in[15];
  const float* core_in_w  = (const float*)d_in[16];
  const float* core_conv_w= (const float*)d_in[17];
  const float* core_conv_b= (const float*)d_in[18];
  const float* core_dtb   = (const float*)d_in[19];
  const float* core_A_log = (const float*)d_in[20];
  const float* core_D     = (const float*)d_in[21];
  const float* core_gw    = (const float*)d_in[22];
  const float* core_out_w = (const float*)d_in[23];
  const float* loop_norm_w= (const float*)d_in[24];
  const float* life_gate  = (const float*)d_in[25];
  const float* norm_f_w   = (const float*)d_in[26];
  const float* lm_head_w  = (const float*)d_in[27];
  (void)in_sizes; (void)n_in; (void)out_size; (void)ws_size;

  char* pb = (char*)d_ws;
  auto balloc = [&](size_t bytes){
    char* q = pb; pb += (bytes + 255) & ~(size_t)255; return q;
  };
  WSP w;
  w.x    = (float*)balloc((size_t)Mtok*Dm*4);
  w.res  = (float*)balloc((size_t)Mtok*Dm*4);
  w.xp   = (float*)balloc((size_t)Mtok*Dm*4);
  w.ctot = (float*)balloc((size_t)Bsz*Hn*NCH*4);
  w.Sc   = (float*)balloc((size_t)Bsz*Hn*NCH*4096*4);
  w.hst  = (float*)balloc((size_t)Bsz*Hn*NCH*4096*4);
  w.part = (float*)balloc((size_t)4*Mtok*Dm*4);
  w.zxh  = (unsigned short*)balloc((size_t)Mtok*DPROJc*2);
  w.yh   = (unsigned short*)balloc((size_t)Mtok*DINc*2);
  w.ub   = (unsigned short*)balloc((size_t)Mtok*Dm*2);
  w.yb   = (unsigned short*)balloc((size_t)Mtok*DINc*2);

  const size_t IWN = (size_t)DPROJc*Dm;      // 2,476,032
  const size_t OWN = (size_t)Dm*DINc;        // 1,179,648
  const size_t HWN = (size_t)Vv*Dm;          // 38,621,184
  w.wib = (unsigned short*)balloc(13*IWN*2);
  w.wob = (unsigned short*)balloc(13*OWN*2);
  w.whb = (unsigned short*)balloc(HWN*2);

  // ---- one-time (per launch) weight conversion / LoRA merge ----
  k_f2h<<<(6*IWN/4 + 255)/256, 256, 0, stream>>>(in_w,  w.wib, (int)(6*IWN/4));
  k_f2h<<<(6*OWN/4 + 255)/256, 256, 0, stream>>>(out_w, w.wob, (int)(6*OWN/4));
  for (int l=0;l<LLO;l++){
    k_lora_merge_h<<<(IWN/4 + 255)/256, 256, 0, stream>>>(
        in_w + (size_t)(SPL+l)*IWN, lora_in_B + (size_t)l*DPROJc*8,
        lora_in_A + (size_t)l*8*Dm, w.wib + (SPL+l)*IWN, DPROJc, Dm);
    k_lora_merge_h<<<(OWN/4 + 255)/256, 256, 0, stream>>>(
        out_w + (size_t)(SPL+l)*OWN, lora_out_B + (size_t)l*Dm*8,
        lora_out_A + (size_t)l*8*DINc, w.wob + (SPL+l)*OWN, Dm, DINc);
  }
  k_f2h<<<(IWN/4 + 255)/256, 256, 0, stream>>>(core_in_w,  w.wib + 12*IWN, (int)(IWN/4));
  k_f2h<<<(OWN/4 + 255)/256, 256, 0, stream>>>(core_out_w, w.wob + 12*OWN, (int)(OWN/4));
  k_f2h<<<(HWN/4 + 255)/256, 256, 0, stream>>>(lm_head_w, w.whb, (int)(HWN/4));

  k_embed<<<Mtok, 192, 0, stream>>>(ids, emb, w.x);
  hipMemsetAsync(w.res, 0, (size_t)Mtok*Dm*sizeof(float), stream);

  const size_t totMD = (size_t)Mtok*Dm;

  auto mixer_l = [&](int l){
    run_mixer_h(stream, w, w.ub,
        w.wib + (size_t)l*IWN, conv_w + (size_t)l*CONVDc*KC, conv_b + (size_t)l*CONVDc,
        dt_bias + (size_t)l*Hn, A_log + (size_t)l*Hn, D_skip + (size_t)l*Hn,
        gnorm_w + (size_t)l*DINc, w.wob + (size_t)l*OWN);
  };
  // ---- prompt phase ----
  k_addrms<<<Mtok, 256, 0, stream>>>(w.x, w.res, w.ub, norm_w);
  mixer_l(0);
  for (int l=1; l<NL; l++){
    k_addrms_p<<<Mtok, 256, 0, stream>>>(w.part, w.res, w.ub, norm_w + (size_t)l*Dm);
    mixer_l(l);
  }
  k_sum_xp<<<(totMD + 255)/256, 256, 0, stream>>>(w.part, w.x, w.xp);
  // ---- loop phase ----
  for (int i=0;i<NLOOPS;i++){
    k_liferope<<<Mtok, 128, 0, stream>>>(w.x, w.xp, life_gate, (float)i);
    k_addrms<<<Mtok, 256, 0, stream>>>(w.x, w.res, w.ub, norm_w + (size_t)SPL*Dm);
    mixer_l(SPL);
    for (int l=SPL+1; l<NL; l++){
      k_addrms_p<<<Mtok, 256, 0, stream>>>(w.part, w.res, w.ub, norm_w + (size_t)l*Dm);
      mixer_l(l);
    }
    k_f2h_sum<<<(totMD + 255)/256, 256, 0, stream>>>(w.part, w.x, w.ub);
    run_mixer_h(stream, w, w.ub,
        w.wib + 12*IWN, core_conv_w, core_conv_b, core_dtb, core_A_log, core_D,
        core_gw, w.wob + 12*OWN);
    k_rms_p<<<Mtok, 256, 0, stream>>>(w.part, w.x, loop_norm_w);
  }
  // ---- head ----
  k_addrms<<<Mtok, 256, 0, stream>>>(w.x, w.res, w.ub, norm_f_w);
  dim3 gHead((Vv + 127)/128, Mtok/128, 1);
  k_gemm_h<<<gHead, 256, 0, stream>>>(w.ub, w.whb, d_out, Vv, Dm, 1);
}

// Round 6
// 2752.010 us; speedup vs baseline: 2.7689x; 1.5021x over previous
//
#include <hip/hip_runtime.h>
#include <math.h>

// ---------------- constants (match reference) ----------------
constexpr int Bsz   = 2;
constexpr int Tseq  = 512;
constexpr int Mtok  = Bsz * Tseq;      // 1024 tokens
constexpr int Dm    = 768;
constexpr int DINc  = 1536;
constexpr int Hn    = 24;
constexpr int NS    = 64;
constexpr int KC    = 4;
constexpr int DPROJc = 2*DINc + 2*NS + Hn;  // 3224
constexpr int CONVDc = DINc + 2*NS;         // 1664
constexpr int NL    = 12;
constexpr int SPL   = 6;
constexpr int LLO   = 6;
constexpr int NCH   = 8;                   // chunks of 64 along T
constexpr int Vv    = 50288;
constexpr float EPSc = 1e-5f;
constexpr int NLOOPS = 3;                  // n_loops (static in setup_inputs)

#define DEVI __device__ __forceinline__

typedef _Float16 f16x8 __attribute__((ext_vector_type(8)));
typedef float    f32x4 __attribute__((ext_vector_type(4)));

DEVI float siluf(float x){ return x / (1.0f + expf(-x)); }
DEVI float softplusf(float x){ return (x > 20.0f) ? x : log1pf(expf(x)); }
DEVI unsigned short f2h(float f){
  union { _Float16 h; unsigned short u; } c;
  c.h = (_Float16)f;                      // RTNE
  return c.u;
}
DEVI float h2f(unsigned short u){
  union { unsigned short u; _Float16 h; } c;
  c.u = u; return (float)c.h;
}

// async global->LDS, 16 bytes per lane; LDS dest = wave-uniform base + lane*16
DEVI void gload16(const void* g, void* l){
  __builtin_amdgcn_global_load_lds(
      (const __attribute__((address_space(1))) void*)g,
      (__attribute__((address_space(3))) void*)l, 16, 0, 0);
}

DEVI float blk_reduce256(float v, float* sh){
  #pragma unroll
  for (int o = 32; o; o >>= 1) v += __shfl_down(v, o);
  int lane = threadIdx.x & 63, w = threadIdx.x >> 6;
  if (lane == 0) sh[w] = v;
  __syncthreads();
  return sh[0] + sh[1] + sh[2] + sh[3];
}

// ---------------- small kernels ----------------
__global__ void k_embed(const int* __restrict__ ids, const float* __restrict__ emb,
                        float* __restrict__ x){
  int m = blockIdx.x;
  int id = ids[m];
  const float4* src = (const float4*)(emb + (size_t)id * Dm);
  float4* dst = (float4*)(x + (size_t)m * Dm);
  int i = threadIdx.x;            // blockDim = 192 = 768/4
  dst[i] = src[i];
}

// f32 -> fp16 convert, 4 elems/thread
__global__ void k_f2h(const float* __restrict__ in, unsigned short* __restrict__ out, int n4){
  int e = blockIdx.x*256 + threadIdx.x;
  if (e >= n4) return;
  float4 v = ((const float4*)in)[e];
  ushort4 o; o.x=f2h(v.x); o.y=f2h(v.y); o.z=f2h(v.z); o.w=f2h(v.w);
  ((ushort4*)out)[e] = o;
}

// res = x + res ; ub = fp16(rms(res) * w)
__global__ __launch_bounds__(256) void k_addrms(const float* __restrict__ xin,
    float* __restrict__ res, unsigned short* __restrict__ ub,
    const float* __restrict__ w){
  int m = blockIdx.x, tid = threadIdx.x;
  __shared__ float sh[4];
  const float* xr = xin + (size_t)m*Dm;
  float* rr = res + (size_t)m*Dm;
  float r[3]; float ss = 0.f;
  #pragma unroll
  for (int k=0;k<3;k++){ int e = tid + k*256; float v = xr[e] + rr[e]; r[k]=v; ss += v*v; }
  ss = blk_reduce256(ss, sh);
  float rs = 1.0f / sqrtf(ss/(float)Dm + EPSc);
  #pragma unroll
  for (int k=0;k<3;k++){
    int e = tid + k*256;
    rr[e] = r[k];
    ub[(size_t)m*Dm+e] = f2h(r[k]*rs*w[e]);
  }
}

// res = (sum of 4 split-K partials) + res ; ub = fp16(rms(res)*w)
__global__ __launch_bounds__(256) void k_addrms_p(const float* __restrict__ part,
    float* __restrict__ res, unsigned short* __restrict__ ub,
    const float* __restrict__ w){
  int m = blockIdx.x, tid = threadIdx.x;
  __shared__ float sh[4];
  const size_t tot = (size_t)Mtok*Dm;
  float* rr = res + (size_t)m*Dm;
  float r[3]; float ss = 0.f;
  #pragma unroll
  for (int k=0;k<3;k++){
    int e = tid + k*256;
    size_t idx = (size_t)m*Dm + e;
    float v = rr[e] + part[idx] + part[tot+idx] + part[2*tot+idx] + part[3*tot+idx];
    r[k]=v; ss += v*v;
  }
  ss = blk_reduce256(ss, sh);
  float rs = 1.0f / sqrtf(ss/(float)Dm + EPSc);
  #pragma unroll
  for (int k=0;k<3;k++){
    int e = tid + k*256;
    rr[e] = r[k];
    ub[(size_t)m*Dm+e] = f2h(r[k]*rs*w[e]);
  }
}

// x = sum parts ; xp = x   (prompt-end snapshot)
__global__ void k_sum_xp(const float* __restrict__ part, float* __restrict__ x,
                         float* __restrict__ xp){
  size_t e = (size_t)blockIdx.x*256 + threadIdx.x;
  const size_t tot = (size_t)Mtok*Dm;
  if (e >= tot) return;
  float v = part[e] + part[tot+e] + part[2*tot+e] + part[3*tot+e];
  x[e] = v; xp[e] = v;
}

// x = sum parts ; ub = fp16(x)   (core-mixer input)
__global__ void k_f2h_sum(const float* __restrict__ part, float* __restrict__ x,
                          unsigned short* __restrict__ ub){
  size_t e = (size_t)blockIdx.x*256 + threadIdx.x;
  const size_t tot = (size_t)Mtok*Dm;
  if (e >= tot) return;
  float v = part[e] + part[tot+e] + part[2*tot+e] + part[3*tot+e];
  x[e] = v; ub[e] = f2h(v);
}

// x = rms(x + sum parts) * w   (loop norm, in-place)
__global__ __launch_bounds__(256) void k_rms_p(const float* __restrict__ part,
    float* __restrict__ x, const float* __restrict__ w){
  int m = blockIdx.x, tid = threadIdx.x;
  __shared__ float sh[4];
  const size_t tot = (size_t)Mtok*Dm;
  float* xr = x + (size_t)m*Dm;
  float r[3]; float ss = 0.f;
  #pragma unroll
  for (int k=0;k<3;k++){
    int e = tid + k*256;
    size_t idx = (size_t)m*Dm + e;
    float v = xr[e] + part[idx] + part[tot+idx] + part[2*tot+idx] + part[3*tot+idx];
    r[k]=v; ss += v*v;
  }
  ss = blk_reduce256(ss, sh);
  float rs = 1.0f / sqrtf(ss/(float)Dm + EPSc);
  #pragma unroll
  for (int k=0;k<3;k++){ int e = tid + k*256; xr[e] = r[k]*rs*w[e]; }
}

// x = rope(x + gate*xp, loop_i)
__global__ __launch_bounds__(128) void k_liferope(float* __restrict__ x,
    const float* __restrict__ xp, const float* __restrict__ gate, float iF){
  int m = blockIdx.x, tid = threadIdx.x;
  float* xr = x + (size_t)m*Dm;
  const float* pr = xp + (size_t)m*Dm;
  #pragma unroll
  for (int k=0;k<3;k++){
    int j = tid + k*128;               // pair index < 384
    int d0 = 2*j, d1 = d0+1;
    float v0 = xr[d0] + gate[d0]*pr[d0];
    float v1 = xr[d1] + gate[d1]*pr[d1];
    float invf = expf(-9.210340371976184f * ((float)(2*j) * (1.0f/768.0f)));
    float f = iF * invf;
    float cv = cosf(f), sv = sinf(f);
    xr[d0] = v0*cv - v1*sv;
    xr[d1] = v1*cv + v0*sv;
  }
}

// ---------------- fp16 MFMA GEMM: C[M,N] = A[M,K] * W[N,K]^T ----------------
// 128x128 tile, 4 waves (2x2), each wave 64x64 via 4x4 mfma_f32_16x16x32_f16.
// BK=64, async global_load_lds(16B) into double-buffered LDS; XOR swizzle
// applied on the per-lane GLOBAL source column (LDS dest stays linear) and on
// the LDS read side (same involution). Counted s_waitcnt vmcnt(8) + raw
// s_barrier keeps next-tile loads in flight across the barrier (T3/T4 recipe).
// Bijective XCD-chunk block remap (m-fastest inside a chunk) for weight-panel
// L2 locality.
// outmode: 0 = f32 split-K partial (KS=gridDim.z), 1 = f32 direct, 2 = fp16 direct
__global__ __launch_bounds__(256) void k_gemm_h(
    const unsigned short* __restrict__ A,
    const unsigned short* __restrict__ Bw,
    void* __restrict__ Cv, int Nd, int Kd, int outmode){
  alignas(16) __shared__ unsigned short lA[2][128*64];
  alignas(16) __shared__ unsigned short lB[2][128*64];
  const int tid  = threadIdx.x;
  const int lane = tid & 63;
  const int wv   = tid >> 6;
  const int wm   = wv >> 1, wn = wv & 1;
  // bijective XCD-chunk swizzle
  const int gx = gridDim.x, gy = gridDim.y;
  const int nwg = gx*gy;
  const int flat = blockIdx.x + gx*blockIdx.y;
  const int q = nwg >> 3, r = nwg & 7;
  const int xcd = flat & 7, pos = flat >> 3;
  const int lg = (xcd < r ? xcd*(q+1) : r*(q+1) + (xcd - r)*q) + pos;
  const int m_idx = lg % gy, n_idx = lg / gy;
  const int n0 = n_idx * 128;
  const int m0 = m_idx * 128;
  const int KS = gridDim.z;
  const int kchunk = Kd / KS;         // multiple of 64
  const int kbeg = blockIdx.z * kchunk;
  const int nsteps = kchunk / 64;

  f32x4 acc[4][4] = {};

  // 8 global_load_lds per thread per tile (4 A + 4 B), linear LDS dest.
  auto stage = [&](int buf, int k0){
    #pragma unroll
    for (int i=0;i<4;i++){
      int seg = tid + i*256;
      int row = seg >> 3;
      int c8  = (seg & 7) ^ (row & 7);       // pre-swizzled source column
      gload16(A + (size_t)(m0 + row)*Kd + k0 + c8*8, &lA[buf][seg*8]);
      int rn = n0 + row; rn = (rn < Nd) ? rn : (Nd - 1);
      gload16(Bw + (size_t)rn*Kd + k0 + c8*8, &lB[buf][seg*8]);
    }
  };

  stage(0, kbeg);
  for (int t=0; t<nsteps; ++t){
    const int cur = t & 1;
    if (t+1 < nsteps){
      stage(cur^1, kbeg + (t+1)*64);
      __builtin_amdgcn_sched_barrier(0);
      asm volatile("s_waitcnt vmcnt(8)" ::: "memory");   // tile t landed; t+1 in flight
    } else {
      asm volatile("s_waitcnt vmcnt(0)" ::: "memory");
    }
    __builtin_amdgcn_s_barrier();
    __builtin_amdgcn_sched_barrier(0);
    #pragma unroll
    for (int kk=0; kk<2; kk++){
      f16x8 af[4], bfr[4];
      #pragma unroll
      for (int f=0; f<4; f++){
        int rowa = wm*64 + f*16 + (lane & 15);
        int ba = rowa*128 + ((kk*64 + (lane>>4)*16) ^ ((rowa & 7) << 4));
        af[f] = *(const f16x8*)((const char*)&lA[cur][0] + ba);
        int rowb = wn*64 + f*16 + (lane & 15);
        int bb = rowb*128 + ((kk*64 + (lane>>4)*16) ^ ((rowb & 7) << 4));
        bfr[f] = *(const f16x8*)((const char*)&lB[cur][0] + bb);
      }
      #pragma unroll
      for (int fm=0; fm<4; fm++)
        #pragma unroll
        for (int fn=0; fn<4; fn++)
          acc[fm][fn] = __builtin_amdgcn_mfma_f32_16x16x32_f16(af[fm], bfr[fn], acc[fm][fn], 0, 0, 0);
    }
    __builtin_amdgcn_s_barrier();     // reads of lds[cur] done before overwrite
  }

  #pragma unroll
  for (int fm=0; fm<4; fm++){
    int mbase = m0 + wm*64 + fm*16 + ((lane>>4)<<2);
    #pragma unroll
    for (int fn=0; fn<4; fn++){
      int n = n0 + wn*64 + fn*16 + (lane & 15);
      if (n < Nd){
        #pragma unroll
        for (int rr=0;rr<4;rr++){
          size_t idx = (size_t)(mbase + rr)*Nd + n;
          float v = acc[fm][fn][rr];
          if (outmode == 0){
            float* Cb = (float*)Cv + (size_t)blockIdx.z*((size_t)Mtok*Nd);
            Cb[idx] = v;
          } else if (outmode == 1){
            ((float*)Cv)[idx] = v;
          } else {
            ((unsigned short*)Cv)[idx] = f2h(v);
          }
        }
      }
    }
  }
}

// ---------------- fused weight prep ----------------
// grid.y = 13 layers: 0..5 plain f2h from W12, 6..11 LoRA-merge, 12 = core.
__global__ void k_prep_in(const float* __restrict__ W12, const float* __restrict__ Wc,
    const float* __restrict__ lA, const float* __restrict__ lB,
    unsigned short* __restrict__ out){
  const int tot4 = DPROJc*Dm/4;
  int e4 = blockIdx.x*256 + threadIdx.x;
  if (e4 >= tot4) return;
  int l = blockIdx.y;
  const float* W = (l < 12) ? W12 + (size_t)l*DPROJc*Dm : Wc;
  const int k4n = Dm/4;
  int n = e4 / k4n, k4 = e4 - n*k4n;
  float4 wv = *(const float4*)(W + (size_t)n*Dm + k4*4);
  float s0=wv.x, s1=wv.y, s2=wv.z, s3=wv.w;
  if (l >= SPL && l < 12){
    int ll = l - SPL;
    const float* Bl = lB + (size_t)ll*DPROJc*8;
    const float* Al = lA + (size_t)ll*8*Dm;
    #pragma unroll
    for (int r=0;r<8;r++){
      float b = 2.0f * Bl[n*8+r];
      float4 a = *(const float4*)(Al + (size_t)r*Dm + k4*4);
      s0 += b*a.x; s1 += b*a.y; s2 += b*a.z; s3 += b*a.w;
    }
  }
  ushort4 o; o.x=f2h(s0); o.y=f2h(s1); o.z=f2h(s2); o.w=f2h(s3);
  ((ushort4*)(out + (size_t)l*DPROJc*Dm))[e4] = o;
}

__global__ void k_prep_out(const float* __restrict__ W12, const float* __restrict__ Wc,
    const float* __restrict__ lA, const float* __restrict__ lB,
    unsigned short* __restrict__ out){
  const int tot4 = Dm*DINc/4;
  int e4 = blockIdx.x*256 + threadIdx.x;
  if (e4 >= tot4) return;
  int l = blockIdx.y;
  const float* W = (l < 12) ? W12 + (size_t)l*Dm*DINc : Wc;
  const int k4n = DINc/4;
  int n = e4 / k4n, k4 = e4 - n*k4n;
  float4 wv = *(const float4*)(W + (size_t)n*DINc + k4*4);
  float s0=wv.x, s1=wv.y, s2=wv.z, s3=wv.w;
  if (l >= SPL && l < 12){
    int ll = l - SPL;
    const float* Bl = lB + (size_t)ll*Dm*8;
    const float* Al = lA + (size_t)ll*8*DINc;
    #pragma unroll
    for (int r=0;r<8;r++){
      float b = 2.0f * Bl[n*8+r];
      float4 a = *(const float4*)(Al + (size_t)r*DINc + k4*4);
      s0 += b*a.x; s1 += b*a.y; s2 += b*a.z; s3 += b*a.w;
    }
  }
  ushort4 o; o.x=f2h(s0); o.y=f2h(s1); o.z=f2h(s2); o.w=f2h(s3);
  ((ushort4*)(out + (size_t)l*Dm*DINc))[e4] = o;
}

// ---------------- SSD scan, MFMA + fused conv ----------------
// LDS fragment loaders: operand layout row=lane&15(+16*f+32*wz), k=(lane>>4)*8+j
DEVI f16x8 ldfrag(const unsigned short (*T)[72], int row, int k0){
  return *(const f16x8*)&T[row][k0];
}

// k_s1: fused conv(x,B) + dt-scan + chunk-state via MFMA.
// Writes S^T[bh][c][p][n] (f32) and per-chunk decay totals ctot.
__global__ __launch_bounds__(256) void k_s1(const unsigned short* __restrict__ zxh,
    const float* __restrict__ cw, const float* __restrict__ cb,
    const float* __restrict__ dtb, const float* __restrict__ alog,
    float* __restrict__ S, float* __restrict__ ctot){
  int bh = blockIdx.x; int b = bh / Hn, h = bh % Hn; int c = blockIdx.y;
  __shared__ unsigned short XT[64][72];    // XT[p][t] = x[t][p]
  __shared__ unsigned short BwT[64][72];   // BwT[n][t] = w_t * B[t][n]
  __shared__ float wv[64];
  int tid = threadIdx.x;
  int base_m = b*Tseq + c*64;
  // --- dt scan (wave 0) ---
  if (tid < 64){
    float Av = -expf(alog[h]);
    float zdt = h2f(zxh[(size_t)(base_m+tid)*DPROJc + DINc + CONVDc + h]) + dtb[h];
    float dt = softplusf(zdt);
    float s = dt * Av;
    #pragma unroll
    for (int o=1;o<64;o<<=1){ float v = __shfl_up(s, o); if (tid >= o) s += v; }
    if (tid == 63) ctot[bh*NCH + c] = s;
    float ce = __shfl(s, 63);
    wv[tid] = expf(ce - s) * dt;
  }
  __syncthreads();
  int ch = tid & 63;          // channel index (p for X pass, n for B pass)
  int t0 = (tid >> 6) * 16;   // this thread covers t0..t0+15
  int tl = c*64 + t0;         // batch-local row of t0
  // --- X pass: conv channel h*64+ch -> XT[ch][t] ---
  {
    int cc = h*64 + ch;
    float4 w4 = *(const float4*)&cw[cc*KC];
    float bias = cb[cc];
    const unsigned short* zp = zxh + (size_t)base_m*DPROJc + DINc + cc;
    float v0 = (tl >= 3) ? h2f(zp[(long)(t0-3)*DPROJc]) : 0.f;
    float v1 = (tl >= 2) ? h2f(zp[(long)(t0-2)*DPROJc]) : 0.f;
    float v2 = (tl >= 1) ? h2f(zp[(long)(t0-1)*DPROJc]) : 0.f;
    #pragma unroll
    for (int i=0;i<16;i++){
      float v3 = h2f(zp[(long)(t0+i)*DPROJc]);
      float o = bias + w4.x*v0 + w4.y*v1 + w4.z*v2 + w4.w*v3;
      XT[ch][t0+i] = f2h(siluf(o));
      v0=v1; v1=v2; v2=v3;
    }
  }
  // --- B pass: conv channel DINc+ch -> BwT[ch][t] = w_t * B ---
  {
    int cc = DINc + ch;
    float4 w4 = *(const float4*)&cw[cc*KC];
    float bias = cb[cc];
    const unsigned short* zp = zxh + (size_t)base_m*DPROJc + DINc + cc;
    float v0 = (tl >= 3) ? h2f(zp[(long)(t0-3)*DPROJc]) : 0.f;
    float v1 = (tl >= 2) ? h2f(zp[(long)(t0-2)*DPROJc]) : 0.f;
    float v2 = (tl >= 1) ? h2f(zp[(long)(t0-1)*DPROJc]) : 0.f;
    #pragma unroll
    for (int i=0;i<16;i++){
      float v3 = h2f(zp[(long)(t0+i)*DPROJc]);
      float o = bias + w4.x*v0 + w4.y*v1 + w4.z*v2 + w4.w*v3;
      BwT[ch][t0+i] = f2h(siluf(o) * wv[t0+i]);
      v0=v1; v1=v2; v2=v3;
    }
  }
  __syncthreads();
  // --- S^T[p][n] = sum_t XT[p][t] * BwT[n][t] ---
  int lane = tid & 63, wid = tid >> 6, wmp = wid >> 1, wnn = wid & 1;
  f32x4 acc[2][2] = {};
  #pragma unroll
  for (int kk=0; kk<2; kk++){
    int k0 = kk*32 + (lane>>4)*8;
    f16x8 a[2], bf[2];
    #pragma unroll
    for (int f=0; f<2; f++){
      a[f]  = ldfrag(XT,  wmp*32 + f*16 + (lane&15), k0);
      bf[f] = ldfrag(BwT, wnn*32 + f*16 + (lane&15), k0);
    }
    #pragma unroll
    for (int fm=0; fm<2; fm++)
      #pragma unroll
      for (int fn=0; fn<2; fn++)
        acc[fm][fn] = __builtin_amdgcn_mfma_f32_16x16x32_f16(a[fm], bf[fn], acc[fm][fn], 0, 0, 0);
  }
  float* Sb = S + ((size_t)(bh*NCH + c))*4096;
  #pragma unroll
  for (int fm=0; fm<2; fm++)
    #pragma unroll
    for (int fn=0; fn<2; fn++)
      #pragma unroll
      for (int rg=0; rg<4; rg++){
        int p = wmp*32 + fm*16 + ((lane>>4)<<2) + rg;
        int n = wnn*32 + fn*16 + (lane&15);
        Sb[p*64 + n] = acc[fm][fn][rg];
      }
}

// sequential over chunks: hst[bh][c] = state at chunk start (elementwise, layout-agnostic)
__global__ void k_s2(const float* __restrict__ S, const float* __restrict__ ctot,
                     float* __restrict__ hst){
  int gid = blockIdx.x*256 + threadIdx.x;
  int bh = gid >> 12; int e = gid & 4095;
  float hv = 0.f;
  #pragma unroll
  for (int c=0;c<NCH;c++){
    size_t idx = ((size_t)(bh*NCH + c))*4096 + e;
    hst[idx] = hv;
    float Ac = expf(ctot[bh*NCH + c]);
    hv = Ac*hv + S[idx];
  }
}

// k_s3: fused conv(x,B,C) + dt-scan + within-chunk attention-form + state + D skip.
// All four 64^3 matmuls via MFMA. Writes y fp16.
__global__ __launch_bounds__(256) void k_s3(const unsigned short* __restrict__ zxh,
    const float* __restrict__ cw, const float* __restrict__ cb,
    const float* __restrict__ dtb, const float* __restrict__ alog,
    const float* __restrict__ hst, const float* __restrict__ Dsk,
    unsigned short* __restrict__ y){
  int bh = blockIdx.x; int b = bh / Hn, h = bh % Hn; int c = blockIdx.y;
  __shared__ unsigned short Ch[64][72];   // Ch[t][n]
  __shared__ unsigned short Bh[64][72];   // Bh[s][n]
  __shared__ unsigned short XhT[64][72];  // XhT[p][t] = x[t][p]
  __shared__ unsigned short hT[64][72];   // hT[p][n] (= hst stored [p][n])
  __shared__ unsigned short Mh[64][72];   // Mh[t][s]
  __shared__ float cumS[64], dtS[64];
  int tid = threadIdx.x;
  int base_m = b*Tseq + c*64;
  // --- dt scan ---
  if (tid < 64){
    float Av = -expf(alog[h]);
    float zdt = h2f(zxh[(size_t)(base_m+tid)*DPROJc + DINc + CONVDc + h]) + dtb[h];
    float dt = softplusf(zdt);
    float s = dt * Av;
    #pragma unroll
    for (int o=1;o<64;o<<=1){ float v = __shfl_up(s, o); if (tid >= o) s += v; }
    cumS[tid] = s;
    dtS[tid]  = dt;
  }
  int ch = tid & 63;
  int t0 = (tid >> 6) * 16;
  int tl = c*64 + t0;
  // --- X pass -> XhT[ch][t] ---
  {
    int cc = h*64 + ch;
    float4 w4 = *(const float4*)&cw[cc*KC];
    float bias = cb[cc];
    const unsigned short* zp = zxh + (size_t)base_m*DPROJc + DINc + cc;
    float v0 = (tl >= 3) ? h2f(zp[(long)(t0-3)*DPROJc]) : 0.f;
    float v1 = (tl >= 2) ? h2f(zp[(long)(t0-2)*DPROJc]) : 0.f;
    float v2 = (tl >= 1) ? h2f(zp[(long)(t0-1)*DPROJc]) : 0.f;
    #pragma unroll
    for (int i=0;i<16;i++){
      float v3 = h2f(zp[(long)(t0+i)*DPROJc]);
      float o = bias + w4.x*v0 + w4.y*v1 + w4.z*v2 + w4.w*v3;
      XhT[ch][t0+i] = f2h(siluf(o));
      v0=v1; v1=v2; v2=v3;
    }
  }
  // --- B pass -> Bh[t][ch] (natural) ---
  {
    int cc = DINc + ch;
    float4 w4 = *(const float4*)&cw[cc*KC];
    float bias = cb[cc];
    const unsigned short* zp = zxh + (size_t)base_m*DPROJc + DINc + cc;
    float v0 = (tl >= 3) ? h2f(zp[(long)(t0-3)*DPROJc]) : 0.f;
    float v1 = (tl >= 2) ? h2f(zp[(long)(t0-2)*DPROJc]) : 0.f;
    float v2 = (tl >= 1) ? h2f(zp[(long)(t0-1)*DPROJc]) : 0.f;
    #pragma unroll
    for (int i=0;i<16;i++){
      float v3 = h2f(zp[(long)(t0+i)*DPROJc]);
      float o = bias + w4.x*v0 + w4.y*v1 + w4.z*v2 + w4.w*v3;
      Bh[t0+i][ch] = f2h(siluf(o));
      v0=v1; v1=v2; v2=v3;
    }
  }
  // --- C pass -> Ch[t][ch] (natural) ---
  {
    int cc = DINc + NS + ch;
    float4 w4 = *(const float4*)&cw[cc*KC];
    float bias = cb[cc];
    const unsigned short* zp = zxh + (size_t)base_m*DPROJc + DINc + cc;
    float v0 = (tl >= 3) ? h2f(zp[(long)(t0-3)*DPROJc]) : 0.f;
    float v1 = (tl >= 2) ? h2f(zp[(long)(t0-2)*DPROJc]) : 0.f;
    float v2 = (tl >= 1) ? h2f(zp[(long)(t0-1)*DPROJc]) : 0.f;
    #pragma unroll
    for (int i=0;i<16;i++){
      float v3 = h2f(zp[(long)(t0+i)*DPROJc]);
      float o = bias + w4.x*v0 + w4.y*v1 + w4.z*v2 + w4.w*v3;
      Ch[t0+i][ch] = f2h(siluf(o));
      v0=v1; v1=v2; v2=v3;
    }
  }
  // --- hT stage (hst already [p][n]) ---
  {
    const float* hb = hst + ((size_t)(bh*NCH + c))*4096;
    for (int e4 = tid; e4 < 1024; e4 += 256){
      float4 hv = ((const float4*)hb)[e4];
      int p = (e4 << 2) >> 6, n = (e4 << 2) & 63;
      ushort4 o; o.x=f2h(hv.x); o.y=f2h(hv.y); o.z=f2h(hv.z); o.w=f2h(hv.w);
      *(ushort4*)&hT[p][n] = o;
    }
  }
  __syncthreads();
  int lane = tid & 63, wid = tid >> 6, wmt = wid >> 1, wns = wid & 1;
  // --- G[t][s] = sum_n Ch[t][n] Bh[s][n] ---
  f32x4 g[2][2] = {};
  #pragma unroll
  for (int kk=0; kk<2; kk++){
    int k0 = kk*32 + (lane>>4)*8;
    f16x8 a[2], bf[2];
    #pragma unroll
    for (int f=0; f<2; f++){
      a[f]  = ldfrag(Ch, wmt*32 + f*16 + (lane&15), k0);
      bf[f] = ldfrag(Bh, wns*32 + f*16 + (lane&15), k0);
    }
    #pragma unroll
    for (int fm=0; fm<2; fm++)
      #pragma unroll
      for (int fn=0; fn<2; fn++)
        g[fm][fn] = __builtin_amdgcn_mfma_f32_16x16x32_f16(a[fm], bf[fn], g[fm][fn], 0, 0, 0);
  }
  // --- mask + decay -> Mh[t][s] fp16 ---
  #pragma unroll
  for (int fm=0; fm<2; fm++)
    #pragma unroll
    for (int fn=0; fn<2; fn++)
      #pragma unroll
      for (int rg=0; rg<4; rg++){
        int t = wmt*32 + fm*16 + ((lane>>4)<<2) + rg;
        int s = wns*32 + fn*16 + (lane&15);
        float val = (s <= t) ? expf(cumS[t] - cumS[s]) * dtS[s] * g[fm][fn][rg] : 0.f;
        Mh[t][s] = f2h(val);
      }
  __syncthreads();
  // --- accL[t][p] = sum_s Mh[t][s] XhT[p][s]; accS[t][p] = sum_n Ch[t][n] hT[p][n] ---
  f32x4 aL[2][2] = {}, aS[2][2] = {};
  #pragma unroll
  for (int kk=0; kk<2; kk++){
    int k0 = kk*32 + (lane>>4)*8;
    f16x8 m_[2], x_[2], c_[2], h_[2];
    #pragma unroll
    for (int f=0; f<2; f++){
      m_[f] = ldfrag(Mh,  wmt*32 + f*16 + (lane&15), k0);
      x_[f] = ldfrag(XhT, wns*32 + f*16 + (lane&15), k0);
      c_[f] = ldfrag(Ch,  wmt*32 + f*16 + (lane&15), k0);
      h_[f] = ldfrag(hT,  wns*32 + f*16 + (lane&15), k0);
    }
    #pragma unroll
    for (int fm=0; fm<2; fm++)
      #pragma unroll
      for (int fn=0; fn<2; fn++){
        aL[fm][fn] = __builtin_amdgcn_mfma_f32_16x16x32_f16(m_[fm], x_[fn], aL[fm][fn], 0, 0, 0);
        aS[fm][fn] = __builtin_amdgcn_mfma_f32_16x16x32_f16(c_[fm], h_[fn], aS[fm][fn], 0, 0, 0);
      }
  }
  // --- epilogue: y = accL + exp(cum_t)*accS + D*x ---
  float Dh = Dsk[h];
  #pragma unroll
  for (int fm=0; fm<2; fm++)
    #pragma unroll
    for (int fn=0; fn<2; fn++)
      #pragma unroll
      for (int rg=0; rg<4; rg++){
        int t = wmt*32 + fm*16 + ((lane>>4)<<2) + rg;
        int p = wns*32 + fn*16 + (lane&15);
        float Pt = expf(cumS[t]);
        float xv = h2f(XhT[p][t]);
        float o = aL[fm][fn][rg] + Pt*aS[fm][fn][rg] + Dh*xv;
        y[(size_t)(base_m+t)*DINc + h*64 + p] = f2h(o);
      }
}

// yb = fp16(rms(y * silu(z)) * gw) ; y fp16, z from zxh fp16
__global__ __launch_bounds__(256) void k_gate(const unsigned short* __restrict__ zxh,
    const unsigned short* __restrict__ y, unsigned short* __restrict__ yb,
    const float* __restrict__ gw){
  int m = blockIdx.x, tid = threadIdx.x;
  __shared__ float sh[4];
  const unsigned short* zr = zxh + (size_t)m*DPROJc;
  const unsigned short* yr = y + (size_t)m*DINc;
  float g[6]; float ss = 0.f;
  #pragma unroll
  for (int k=0;k<6;k++){
    int e = tid + k*256;
    float z = h2f(zr[e]);
    float v = h2f(yr[e]) * siluf(z);
    g[k] = v; ss += v*v;
  }
  ss = blk_reduce256(ss, sh);
  float rs = 1.0f / sqrtf(ss/(float)DINc + EPSc);
  #pragma unroll
  for (int k=0;k<6;k++){
    int e = tid + k*256;
    yb[(size_t)m*DINc + e] = f2h(g[k]*rs*gw[e]);
  }
}

// ---------------- host orchestration ----------------
struct WSP {
  float *x,*res,*xp,*ctot,*Sc,*hst,*part;
  unsigned short *zxh,*yh,*ub,*yb,*wib,*wob,*whb;
};

static void run_mixer_h(hipStream_t st, const WSP& w, const unsigned short* ub_in,
    const unsigned short* iw, const float* cw, const float* cb, const float* dtb,
    const float* al, const float* dk, const float* gw, const unsigned short* ow){
  dim3 gIn((DPROJc + 127)/128, Mtok/128, 1);
  k_gemm_h<<<gIn, 256, 0, st>>>(ub_in, iw, w.zxh, DPROJc, Dm, 2);
  k_s1<<<dim3(Bsz*Hn, NCH), 256, 0, st>>>(w.zxh, cw, cb, dtb, al, w.Sc, w.ctot);
  k_s2<<<(Bsz*Hn*4096)/256, 256, 0, st>>>(w.Sc, w.ctot, w.hst);
  k_s3<<<dim3(Bsz*Hn, NCH), 256, 0, st>>>(w.zxh, cw, cb, dtb, al, w.hst, dk, w.yh);
  k_gate<<<Mtok, 256, 0, st>>>(w.zxh, w.yh, w.yb, gw);
  dim3 gOut(Dm/128, Mtok/128, 4);      // split-K=4 partials
  k_gemm_h<<<gOut, 256, 0, st>>>(w.yb, ow, w.part, Dm, DINc, 0);
}

extern "C" void kernel_launch(void* const* d_in, const int* in_sizes, int n_in,
                              void* d_out, int out_size, void* d_ws, size_t ws_size,
                              hipStream_t stream){
  const int*   ids        = (const int*)  d_in[0];
  // d_in[1] = n_loops (device scalar) -- statically 3; graph must be fixed anyway.
  const float* emb        = (const float*)d_in[2];
  const float* norm_w     = (const float*)d_in[3];
  const float* in_w       = (const float*)d_in[4];
  const float* conv_w     = (const float*)d_in[5];
  const float* conv_b     = (const float*)d_in[6];
  const float* dt_bias    = (const float*)d_in[7];
  const float* A_log      = (const float*)d_in[8];
  const float* D_skip     = (const float*)d_in[9];
  const float* gnorm_w    = (const float*)d_in[10];
  const float* out_w      = (const float*)d_in[11];
  const float* lora_in_A  = (const float*)d_in[12];
  const float* lora_in_B  = (const float*)d_in[13];
  const float* lora_out_A = (const float*)d_in[14];
  const float* lora_out_B = (const float*)d_in[15];
  const float* core_in_w  = (const float*)d_in[16];
  const float* core_conv_w= (const float*)d_in[17];
  const float* core_conv_b= (const float*)d_in[18];
  const float* core_dtb   = (const float*)d_in[19];
  const float* core_A_log = (const float*)d_in[20];
  const float* core_D     = (const float*)d_in[21];
  const float* core_gw    = (const float*)d_in[22];
  const float* core_out_w = (const float*)d_in[23];
  const float* loop_norm_w= (const float*)d_in[24];
  const float* life_gate  = (const float*)d_in[25];
  const float* norm_f_w   = (const float*)d_in[26];
  const float* lm_head_w  = (const float*)d_in[27];
  (void)in_sizes; (void)n_in; (void)out_size; (void)ws_size;

  char* pb = (char*)d_ws;
  auto balloc = [&](size_t bytes){
    char* q = pb; pb += (bytes + 255) & ~(size_t)255; return q;
  };
  WSP w;
  w.x    = (float*)balloc((size_t)Mtok*Dm*4);
  w.res  = (float*)balloc((size_t)Mtok*Dm*4);
  w.xp   = (float*)balloc((size_t)Mtok*Dm*4);
  w.ctot = (float*)balloc((size_t)Bsz*Hn*NCH*4);
  w.Sc   = (float*)balloc((size_t)Bsz*Hn*NCH*4096*4);
  w.hst  = (float*)balloc((size_t)Bsz*Hn*NCH*4096*4);
  w.part = (float*)balloc((size_t)4*Mtok*Dm*4);
  w.zxh  = (unsigned short*)balloc((size_t)Mtok*DPROJc*2);
  w.yh   = (unsigned short*)balloc((size_t)Mtok*DINc*2);
  w.ub   = (unsigned short*)balloc((size_t)Mtok*Dm*2);
  w.yb   = (unsigned short*)balloc((size_t)Mtok*DINc*2);

  const size_t IWN = (size_t)DPROJc*Dm;      // 2,476,032
  const size_t OWN = (size_t)Dm*DINc;        // 1,179,648
  const size_t HWN = (size_t)Vv*Dm;          // 38,621,184
  w.wib = (unsigned short*)balloc(13*IWN*2);
  w.wob = (unsigned short*)balloc(13*OWN*2);
  w.whb = (unsigned short*)balloc(HWN*2);

  // ---- one-time (per launch) weight prep: 3 launches ----
  k_prep_in<<<dim3((IWN/4 + 255)/256, 13), 256, 0, stream>>>(
      in_w, core_in_w, lora_in_A, lora_in_B, w.wib);
  k_prep_out<<<dim3((OWN/4 + 255)/256, 13), 256, 0, stream>>>(
      out_w, core_out_w, lora_out_A, lora_out_B, w.wob);
  k_f2h<<<(HWN/4 + 255)/256, 256, 0, stream>>>(lm_head_w, w.whb, (int)(HWN/4));

  k_embed<<<Mtok, 192, 0, stream>>>(ids, emb, w.x);
  hipMemsetAsync(w.res, 0, (size_t)Mtok*Dm*sizeof(float), stream);

  const size_t totMD = (size_t)Mtok*Dm;

  auto mixer_l = [&](int l){
    run_mixer_h(stream, w, w.ub,
        w.wib + (size_t)l*IWN, conv_w + (size_t)l*CONVDc*KC, conv_b + (size_t)l*CONVDc,
        dt_bias + (size_t)l*Hn, A_log + (size_t)l*Hn, D_skip + (size_t)l*Hn,
        gnorm_w + (size_t)l*DINc, w.wob + (size_t)l*OWN);
  };
  // ---- prompt phase ----
  k_addrms<<<Mtok, 256, 0, stream>>>(w.x, w.res, w.ub, norm_w);
  mixer_l(0);
  for (int l=1; l<NL; l++){
    k_addrms_p<<<Mtok, 256, 0, stream>>>(w.part, w.res, w.ub, norm_w + (size_t)l*Dm);
    mixer_l(l);
  }
  k_sum_xp<<<(totMD + 255)/256, 256, 0, stream>>>(w.part, w.x, w.xp);
  // ---- loop phase ----
  for (int i=0;i<NLOOPS;i++){
    k_liferope<<<Mtok, 128, 0, stream>>>(w.x, w.xp, life_gate, (float)i);
    k_addrms<<<Mtok, 256, 0, stream>>>(w.x, w.res, w.ub, norm_w + (size_t)SPL*Dm);
    mixer_l(SPL);
    for (int l=SPL+1; l<NL; l++){
      k_addrms_p<<<Mtok, 256, 0, stream>>>(w.part, w.res, w.ub, norm_w + (size_t)l*Dm);
      mixer_l(l);
    }
    k_f2h_sum<<<(totMD + 255)/256, 256, 0, stream>>>(w.part, w.x, w.ub);
    run_mixer_h(stream, w, w.ub,
        w.wib + 12*IWN, core_conv_w, core_conv_b, core_dtb, core_A_log, core_D,
        core_gw, w.wob + 12*OWN);
    k_rms_p<<<Mtok, 256, 0, stream>>>(w.part, w.x, loop_norm_w);
  }
  // ---- head ----
  k_addrms<<<Mtok, 256, 0, stream>>>(w.x, w.res, w.ub, norm_f_w);
  dim3 gHead((Vv + 127)/128, Mtok/128, 1);
  k_gemm_h<<<gHead, 256, 0, stream>>>(w.ub, w.whb, d_out, Vv, Dm, 1);
}